// Round 2
// baseline (390.550 us; speedup 1.0000x reference)
//
#include <hip/hip_runtime.h>

typedef short s16x4 __attribute__((ext_vector_type(4)));
typedef short s16x8 __attribute__((ext_vector_type(8)));
typedef float f32x4 __attribute__((ext_vector_type(4)));
typedef unsigned short u16;

__device__ __forceinline__ u16 f2b(float f) {
    union { float f; unsigned u; } v; v.f = f;
    unsigned r = v.u + 0x7FFFu + ((v.u >> 16) & 1u);
    return (u16)(r >> 16);
}

// ---------------- cast x (fp32) -> bf16 ----------------
__global__ __launch_bounds__(256) void cast_x_kernel(const float* __restrict__ x,
                                                     u16* __restrict__ xb) {
    size_t i = ((size_t)blockIdx.x * 256 + threadIdx.x) * 8;
    const f32x4* s = (const f32x4*)(x + i);
    f32x4 a = s[0], b = s[1];
    s16x8 o;
    o[0] = (short)f2b(a[0]); o[1] = (short)f2b(a[1]);
    o[2] = (short)f2b(a[2]); o[3] = (short)f2b(a[3]);
    o[4] = (short)f2b(b[0]); o[5] = (short)f2b(b[1]);
    o[6] = (short)f2b(b[2]); o[7] = (short)f2b(b[3]);
    *(s16x8*)(xb + i) = o;
}

// ------------- transpose + cast weight: W[K][N] fp32 -> Wt[N][K] bf16 -------------
__global__ __launch_bounds__(256) void wcast_kernel(const float* __restrict__ W,
                                                    u16* __restrict__ Wt, int K, int N) {
    int gid = blockIdx.x * 256 + threadIdx.x;
    if (gid >= K * N) return;
    int n = gid / K, k = gid - n * K;
    Wt[gid] = f2b(W[(size_t)k * N + n]);
}

// ---------------- gate: idx = argmax(x @ Wg) ----------------
__global__ __launch_bounds__(256) void gate_kernel(const float* __restrict__ x,
                                                   const float* __restrict__ Wg,
                                                   int* __restrict__ idx,
                                                   float* __restrict__ out) {
    int t = blockIdx.x * 4 + (threadIdx.x >> 6);
    int lane = threadIdx.x & 63;
    const float* xr = x + (size_t)t * 768;
    float z0 = 0.f, z1 = 0.f, z2 = 0.f;
    for (int c = lane; c < 768; c += 64) {
        float xv = xr[c];
        z0 = fmaf(xv, Wg[c * 3 + 0], z0);
        z1 = fmaf(xv, Wg[c * 3 + 1], z1);
        z2 = fmaf(xv, Wg[c * 3 + 2], z2);
    }
    for (int o = 32; o; o >>= 1) {
        z0 += __shfl_xor(z0, o);
        z1 += __shfl_xor(z1, o);
        z2 += __shfl_xor(z2, o);
    }
    if (lane == 0) {
        int k = 0; float b = z0;
        if (z1 > b) { b = z1; k = 1; }
        if (z2 > b) { b = z2; k = 2; }
        idx[t] = k;
        out[12582912 + t] = (float)k;   // idx output (f32)
    }
}

// ---------------- QKV GEMM: xb[8192][768] @ Wqkv_t -> Q/K/Vt scatter ----------------
__global__ __launch_bounds__(256) void qkv_gemm_kernel(const u16* __restrict__ A,
                                                       const u16* __restrict__ Bt_all,
                                                       u16* __restrict__ Qo,
                                                       u16* __restrict__ Ko,
                                                       u16* __restrict__ Vt) {
    __shared__ u16 As[128 * 72];
    __shared__ u16 Bs[128 * 72];
    const int tid = threadIdx.x;
    const int lane = tid & 63, w = tid >> 6, wm = w >> 1, wn = w & 1;
    const int g = lane >> 4, c15 = lane & 15;
    const int branch = blockIdx.z;
    const int m0 = blockIdx.y * 128, n0 = blockIdx.x * 128;
    const u16* Bt = Bt_all + (size_t)branch * 589824;
    const int Kdim = 768, lda = 768, ldb = 768;

    f32x4 z4 = {0.f, 0.f, 0.f, 0.f};
    f32x4 acc[4][4];
    for (int mi = 0; mi < 4; mi++)
        for (int ni = 0; ni < 4; ni++) acc[mi][ni] = z4;

    for (int k0 = 0; k0 < Kdim; k0 += 64) {
        __syncthreads();
        for (int cidx = 0; cidx < 4; cidx++) {
            int i = cidx * 256 + tid;
            int row = i >> 3, cb = i & 7;
            *(s16x8*)&As[row * 72 + cb * 8] =
                *(const s16x8*)(A + (size_t)(m0 + row) * lda + k0 + cb * 8);
            *(s16x8*)&Bs[row * 72 + cb * 8] =
                *(const s16x8*)(Bt + (size_t)(n0 + row) * ldb + k0 + cb * 8);
        }
        __syncthreads();
        for (int kk = 0; kk < 2; kk++) {
            s16x8 af[4], bf[4];
            for (int i = 0; i < 4; i++) {
                af[i] = *(const s16x8*)&As[(wm * 64 + i * 16 + c15) * 72 + kk * 32 + g * 8];
                bf[i] = *(const s16x8*)&Bs[(wn * 64 + i * 16 + c15) * 72 + kk * 32 + g * 8];
            }
            for (int mi = 0; mi < 4; mi++)
                for (int ni = 0; ni < 4; ni++)
                    acc[mi][ni] = __builtin_amdgcn_mfma_f32_16x16x32_bf16(
                        af[mi], bf[ni], acc[mi][ni], 0, 0, 0);
        }
    }

    // epilogue: scatter into Q [inst][n][64] (x0.125), K [inst][n][64], Vt [inst][d][2048]
    for (int mi = 0; mi < 4; mi++) {
        int r = m0 + wm * 64 + mi * 16 + g * 4;
        int batch = r >> 11, nbase = r & 2047;
        for (int ni = 0; ni < 4; ni++) {
            int cN = n0 + wn * 64 + ni * 16 + c15;
            int p = cN >> 8, h = (cN >> 6) & 3, d = cN & 63;
            size_t hb = (size_t)((branch * 4 + batch) * 4 + h) * 131072;
            f32x4 v = acc[mi][ni];
            if (p == 2) {
                s16x4 pk;
                for (int rg = 0; rg < 4; rg++) pk[rg] = (short)f2b(v[rg]);
                *(s16x4*)(Vt + hb + (size_t)d * 2048 + nbase) = pk;
            } else if (p == 0) {
                for (int rg = 0; rg < 4; rg++)
                    Qo[hb + (size_t)(nbase + rg) * 64 + d] = f2b(v[rg] * 0.125f);
            } else {
                for (int rg = 0; rg < 4; rg++)
                    Ko[hb + (size_t)(nbase + rg) * 64 + d] = f2b(v[rg]);
            }
        }
    }
}

// ---------------- flash attention: one wave = 32 q-rows of one (branch,b,h) ----------------
// 32 k-positions per iteration; PV via 16x16x32 with split-V fragments so the
// QK^T C-layout feeds PV's B-operand with a consistent k-permutation.
__global__ __launch_bounds__(256) void attn_kernel(const u16* __restrict__ Qg,
                                                   const u16* __restrict__ Kg,
                                                   const u16* __restrict__ Vg,
                                                   u16* __restrict__ Og) {
    int wid = (int)((blockIdx.x * 256 + threadIdx.x) >> 6);
    int lane = threadIdx.x & 63;
    int inst = wid >> 6;   // 48 instances
    int qt = wid & 63;     // 64 q-tiles of 32 rows
    int g = lane >> 4, c = lane & 15;
    const u16* Qh = Qg + (size_t)inst * 131072;
    const u16* Kh = Kg + (size_t)inst * 131072;
    const u16* Vh = Vg + (size_t)inst * 131072;

    f32x4 z4 = {0.f, 0.f, 0.f, 0.f};
    s16x8 qf[2][2];
    for (int s = 0; s < 2; s++)
        for (int kk = 0; kk < 2; kk++)
            qf[s][kk] = *(const s16x8*)(Qh + (size_t)(qt * 32 + s * 16 + c) * 64 + kk * 32 + g * 8);

    f32x4 oac[2][4];
    for (int s = 0; s < 2; s++)
        for (int dt = 0; dt < 4; dt++) oac[s][dt] = z4;
    float m[2] = {-1e30f, -1e30f}, ls[2] = {0.f, 0.f};

    for (int kt = 0; kt < 64; kt++) {   // 32 kpos per tile
        const u16* Kb = Kh + (size_t)kt * 32 * 64;
        s16x8 kf[2][2];
        for (int t = 0; t < 2; t++) {
            kf[t][0] = *(const s16x8*)(Kb + (t * 16 + c) * 64 + g * 8);
            kf[t][1] = *(const s16x8*)(Kb + (t * 16 + c) * 64 + 32 + g * 8);
        }
        s16x8 vf[4];
        for (int dt = 0; dt < 4; dt++) {
            const u16* Vr = Vh + (size_t)(dt * 16 + c) * 2048 + kt * 32;
            s16x4 v0 = *(const s16x4*)(Vr + g * 4);
            s16x4 v1 = *(const s16x4*)(Vr + 16 + g * 4);
            s16x8 vv;
            vv[0] = v0[0]; vv[1] = v0[1]; vv[2] = v0[2]; vv[3] = v0[3];
            vv[4] = v1[0]; vv[5] = v1[1]; vv[6] = v1[2]; vv[7] = v1[3];
            vf[dt] = vv;
        }

        for (int s = 0; s < 2; s++) {
            // S^T subtiles [16 kpos][16 q] = K . Q^T (Q pre-scaled by 0.125)
            f32x4 sa0 = __builtin_amdgcn_mfma_f32_16x16x32_bf16(kf[0][0], qf[s][0], z4, 0, 0, 0);
            sa0 = __builtin_amdgcn_mfma_f32_16x16x32_bf16(kf[0][1], qf[s][1], sa0, 0, 0, 0);
            f32x4 sa1 = __builtin_amdgcn_mfma_f32_16x16x32_bf16(kf[1][0], qf[s][0], z4, 0, 0, 0);
            sa1 = __builtin_amdgcn_mfma_f32_16x16x32_bf16(kf[1][1], qf[s][1], sa1, 0, 0, 0);

            float tm = fmaxf(fmaxf(fmaxf(sa0[0], sa0[1]), fmaxf(sa0[2], sa0[3])),
                             fmaxf(fmaxf(sa1[0], sa1[1]), fmaxf(sa1[2], sa1[3])));
            tm = fmaxf(tm, __shfl_xor(tm, 16));
            tm = fmaxf(tm, __shfl_xor(tm, 32));
            float mn = fmaxf(m[s], tm);
            float alpha = __expf(m[s] - mn);
            f32x4 p0, p1;
            p0[0] = __expf(sa0[0] - mn); p0[1] = __expf(sa0[1] - mn);
            p0[2] = __expf(sa0[2] - mn); p0[3] = __expf(sa0[3] - mn);
            p1[0] = __expf(sa1[0] - mn); p1[1] = __expf(sa1[1] - mn);
            p1[2] = __expf(sa1[2] - mn); p1[3] = __expf(sa1[3] - mn);
            float ts = ((p0[0] + p0[1]) + (p0[2] + p0[3]))
                     + ((p1[0] + p1[1]) + (p1[2] + p1[3]));
            ts += __shfl_xor(ts, 16);
            ts += __shfl_xor(ts, 32);
            ls[s] = ls[s] * alpha + ts;
            m[s] = mn;
            s16x8 pb;
            pb[0] = (short)f2b(p0[0]); pb[1] = (short)f2b(p0[1]);
            pb[2] = (short)f2b(p0[2]); pb[3] = (short)f2b(p0[3]);
            pb[4] = (short)f2b(p1[0]); pb[5] = (short)f2b(p1[1]);
            pb[6] = (short)f2b(p1[2]); pb[7] = (short)f2b(p1[3]);
            // O^T[d][q] += Vt . P^T via 16x16x32 (k-permutation consistent on A and B)
            for (int dt = 0; dt < 4; dt++) {
                oac[s][dt] = oac[s][dt] * alpha;
                oac[s][dt] = __builtin_amdgcn_mfma_f32_16x16x32_bf16(
                    vf[dt], pb, oac[s][dt], 0, 0, 0);
            }
        }
    }

    int branch = inst >> 4, batch = (inst >> 2) & 3, h = inst & 3;
    for (int s = 0; s < 2; s++) {
        float inv = 1.0f / ls[s];
        int n = qt * 32 + s * 16 + c;
        u16* dst = Og + ((size_t)(branch * 4 + batch) * 2048 + n) * 256 + h * 64;
        for (int dt = 0; dt < 4; dt++) {
            s16x4 ob;
            for (int rg = 0; rg < 4; rg++) ob[rg] = (short)f2b(oac[s][dt][rg] * inv);
            *(s16x4*)(dst + dt * 16 + g * 4) = ob;
        }
    }
}

// ---------------- proj GEMM: O_b[8192][256] @ Wp_t + bp, select by idx, dual f32 write ----------------
__global__ __launch_bounds__(256) void proj_gemm_kernel(const u16* __restrict__ Oall,
                                                        const u16* __restrict__ Wpt_all,
                                                        const int* __restrict__ idx,
                                                        const float* __restrict__ bp1,
                                                        const float* __restrict__ bp2,
                                                        const float* __restrict__ bp3,
                                                        float* __restrict__ out) {
    __shared__ u16 As[128 * 72];
    __shared__ u16 Bs[128 * 72];
    const int tid = threadIdx.x;
    const int lane = tid & 63, w = tid >> 6, wm = w >> 1, wn = w & 1;
    const int g = lane >> 4, c15 = lane & 15;
    const int branch = blockIdx.z;
    const int m0 = blockIdx.y * 128, n0 = blockIdx.x * 128;
    const u16* A = Oall + (size_t)branch * 8192 * 256;
    const u16* Bt = Wpt_all + (size_t)branch * 196608;
    const float* bp = (branch == 0) ? bp1 : ((branch == 1) ? bp2 : bp3);
    const int Kdim = 256, lda = 256, ldb = 256;

    f32x4 z4 = {0.f, 0.f, 0.f, 0.f};
    f32x4 acc[4][4];
    for (int mi = 0; mi < 4; mi++)
        for (int ni = 0; ni < 4; ni++) acc[mi][ni] = z4;

    for (int k0 = 0; k0 < Kdim; k0 += 64) {
        __syncthreads();
        for (int cidx = 0; cidx < 4; cidx++) {
            int i = cidx * 256 + tid;
            int row = i >> 3, cb = i & 7;
            *(s16x8*)&As[row * 72 + cb * 8] =
                *(const s16x8*)(A + (size_t)(m0 + row) * lda + k0 + cb * 8);
            *(s16x8*)&Bs[row * 72 + cb * 8] =
                *(const s16x8*)(Bt + (size_t)(n0 + row) * ldb + k0 + cb * 8);
        }
        __syncthreads();
        for (int kk = 0; kk < 2; kk++) {
            s16x8 af[4], bf[4];
            for (int i = 0; i < 4; i++) {
                af[i] = *(const s16x8*)&As[(wm * 64 + i * 16 + c15) * 72 + kk * 32 + g * 8];
                bf[i] = *(const s16x8*)&Bs[(wn * 64 + i * 16 + c15) * 72 + kk * 32 + g * 8];
            }
            for (int mi = 0; mi < 4; mi++)
                for (int ni = 0; ni < 4; ni++)
                    acc[mi][ni] = __builtin_amdgcn_mfma_f32_16x16x32_bf16(
                        af[mi], bf[ni], acc[mi][ni], 0, 0, 0);
        }
    }

    for (int mi = 0; mi < 4; mi++) {
        int r = m0 + wm * 64 + mi * 16 + g * 4;
        for (int ni = 0; ni < 4; ni++) {
            int cN = n0 + wn * 64 + ni * 16 + c15;
            float bj = bp[cN];
            f32x4 v = acc[mi][ni];
            for (int rg = 0; rg < 4; rg++) {
                int t = r + rg;
                if (idx[t] == branch) {
                    float wv = v[rg] + bj;
                    out[(size_t)t * 768 + cN] = wv;                 // xo
                    out[6291456u + (size_t)t * 768 + cN] = wv;      // xd
                }
            }
        }
    }
}

extern "C" void kernel_launch(void* const* d_in, const int* in_sizes, int n_in,
                              void* d_out, int out_size, void* d_ws, size_t ws_size,
                              hipStream_t stream) {
    const float* x   = (const float*)d_in[0];
    const float* Wq1 = (const float*)d_in[1];
    const float* Wq2 = (const float*)d_in[2];
    const float* Wq3 = (const float*)d_in[3];
    const float* Wp1 = (const float*)d_in[4];
    const float* bp1 = (const float*)d_in[5];
    const float* Wp2 = (const float*)d_in[6];
    const float* bp2 = (const float*)d_in[7];
    const float* Wp3 = (const float*)d_in[8];
    const float* bp3 = (const float*)d_in[9];
    const float* Wg  = (const float*)d_in[10];
    float* out = (float*)d_out;

    char* ws = (char*)d_ws;
    u16* xb  = (u16*)(ws + 0);          // 12582912 B
    u16* wqt = (u16*)(ws + 12582912);   // 3538944 B  (3x [768][768] bf16, transposed)
    u16* wpt = (u16*)(ws + 16121856);   // 1179648 B  (3x [768][256] bf16, transposed)
    u16* Qb  = (u16*)(ws + 17301504);   // 12582912 B (48 x [2048][64])
    u16* Kb  = (u16*)(ws + 29884416);   // 12582912 B
    u16* Vtb = (u16*)(ws + 42467328);   // 12582912 B (48 x [64][2048])
    u16* Ob  = (u16*)(ws + 55050240);   // 12582912 B (3 x [8192][256])
    int* idx = (int*)(ws + 67633152);   // 32768 B

    cast_x_kernel<<<3072, 256, 0, stream>>>(x, xb);
    wcast_kernel<<<2304, 256, 0, stream>>>(Wq1, wqt + 0 * 589824, 768, 768);
    wcast_kernel<<<2304, 256, 0, stream>>>(Wq2, wqt + 1 * 589824, 768, 768);
    wcast_kernel<<<2304, 256, 0, stream>>>(Wq3, wqt + 2 * 589824, 768, 768);
    wcast_kernel<<<768, 256, 0, stream>>>(Wp1, wpt + 0 * 196608, 256, 768);
    wcast_kernel<<<768, 256, 0, stream>>>(Wp2, wpt + 1 * 196608, 256, 768);
    wcast_kernel<<<768, 256, 0, stream>>>(Wp3, wpt + 2 * 196608, 256, 768);
    gate_kernel<<<2048, 256, 0, stream>>>(x, Wg, idx, out);
    qkv_gemm_kernel<<<dim3(6, 64, 3), 256, 0, stream>>>(xb, wqt, Qb, Kb, Vtb);
    attn_kernel<<<768, 256, 0, stream>>>(Qb, Kb, Vtb, Ob);
    proj_gemm_kernel<<<dim3(6, 64, 3), 256, 0, stream>>>(Ob, wpt, idx, bp1, bp2, bp3, out);
}

// Round 3
// 308.250 us; speedup vs baseline: 1.2670x; 1.2670x over previous
//
#include <hip/hip_runtime.h>

typedef short s16x4 __attribute__((ext_vector_type(4)));
typedef short s16x8 __attribute__((ext_vector_type(8)));
typedef float f32x4 __attribute__((ext_vector_type(4)));
typedef unsigned u32x4 __attribute__((ext_vector_type(4)));
typedef unsigned short u16;

__device__ __forceinline__ u16 f2b(float f) {
    union { float f; unsigned u; } v; v.f = f;
    unsigned r = v.u + 0x7FFFu + ((v.u >> 16) & 1u);
    return (u16)(r >> 16);
}

__device__ __forceinline__ float fexp2(float x) {
    float r; asm("v_exp_f32 %0, %1" : "=v"(r) : "v"(x)); return r;
}

__device__ __forceinline__ unsigned cvtpk(float lo, float hi) {
    unsigned r; asm("v_cvt_pk_bf16_f32 %0, %1, %2" : "=v"(r) : "v"(lo), "v"(hi)); return r;
}

// Q pre-scale: hd^-0.5 * log2(e) so attention uses v_exp_f32 (2^x) directly
#define QSCALE 0.1803368801111244f

// ---------------- cast x (fp32) -> bf16 ----------------
__global__ __launch_bounds__(256) void cast_x_kernel(const float* __restrict__ x,
                                                     u16* __restrict__ xb) {
    size_t i = ((size_t)blockIdx.x * 256 + threadIdx.x) * 8;
    const f32x4* s = (const f32x4*)(x + i);
    f32x4 a = s[0], b = s[1];
    s16x8 o;
    o[0] = (short)f2b(a[0]); o[1] = (short)f2b(a[1]);
    o[2] = (short)f2b(a[2]); o[3] = (short)f2b(a[3]);
    o[4] = (short)f2b(b[0]); o[5] = (short)f2b(b[1]);
    o[6] = (short)f2b(b[2]); o[7] = (short)f2b(b[3]);
    *(s16x8*)(xb + i) = o;
}

// ------------- transpose + cast weight: W[K][N] fp32 -> Wt[N][K] bf16 -------------
__global__ __launch_bounds__(256) void wcast_kernel(const float* __restrict__ W,
                                                    u16* __restrict__ Wt, int K, int N) {
    int gid = blockIdx.x * 256 + threadIdx.x;
    if (gid >= K * N) return;
    int n = gid / K, k = gid - n * K;
    Wt[gid] = f2b(W[(size_t)k * N + n]);
}

// ---------------- gate: idx = argmax(x @ Wg) ----------------
__global__ __launch_bounds__(256) void gate_kernel(const float* __restrict__ x,
                                                   const float* __restrict__ Wg,
                                                   int* __restrict__ idx,
                                                   float* __restrict__ out) {
    int t = blockIdx.x * 4 + (threadIdx.x >> 6);
    int lane = threadIdx.x & 63;
    const float* xr = x + (size_t)t * 768;
    float z0 = 0.f, z1 = 0.f, z2 = 0.f;
    for (int c = lane; c < 768; c += 64) {
        float xv = xr[c];
        z0 = fmaf(xv, Wg[c * 3 + 0], z0);
        z1 = fmaf(xv, Wg[c * 3 + 1], z1);
        z2 = fmaf(xv, Wg[c * 3 + 2], z2);
    }
    for (int o = 32; o; o >>= 1) {
        z0 += __shfl_xor(z0, o);
        z1 += __shfl_xor(z1, o);
        z2 += __shfl_xor(z2, o);
    }
    if (lane == 0) {
        int k = 0; float b = z0;
        if (z1 > b) { b = z1; k = 1; }
        if (z2 > b) { b = z2; k = 2; }
        idx[t] = k;
        out[12582912 + t] = (float)k;   // idx output (f32)
    }
}

// ---------------- QKV GEMM: xb[8192][768] @ Wqkv_t -> Q/K/V scatter ----------------
// Q pre-scaled by QSCALE; V written in PV-fragment slot order.
__global__ __launch_bounds__(256) void qkv_gemm_kernel(const u16* __restrict__ A,
                                                       const u16* __restrict__ Bt_all,
                                                       u16* __restrict__ Qo,
                                                       u16* __restrict__ Ko,
                                                       u16* __restrict__ Vt) {
    __shared__ u16 As[128 * 72];
    __shared__ u16 Bs[128 * 72];
    const int tid = threadIdx.x;
    const int lane = tid & 63, w = tid >> 6, wm = w >> 1, wn = w & 1;
    const int g = lane >> 4, c15 = lane & 15;
    const int branch = blockIdx.z;
    const int m0 = blockIdx.y * 128, n0 = blockIdx.x * 128;
    const u16* Bt = Bt_all + (size_t)branch * 589824;
    const int Kdim = 768, lda = 768, ldb = 768;

    f32x4 z4 = {0.f, 0.f, 0.f, 0.f};
    f32x4 acc[4][4];
    for (int mi = 0; mi < 4; mi++)
        for (int ni = 0; ni < 4; ni++) acc[mi][ni] = z4;

    for (int k0 = 0; k0 < Kdim; k0 += 64) {
        __syncthreads();
        for (int cidx = 0; cidx < 4; cidx++) {
            int i = cidx * 256 + tid;
            int row = i >> 3, cb = i & 7;
            *(s16x8*)&As[row * 72 + cb * 8] =
                *(const s16x8*)(A + (size_t)(m0 + row) * lda + k0 + cb * 8);
            *(s16x8*)&Bs[row * 72 + cb * 8] =
                *(const s16x8*)(Bt + (size_t)(n0 + row) * ldb + k0 + cb * 8);
        }
        __syncthreads();
        for (int kk = 0; kk < 2; kk++) {
            s16x8 af[4], bf[4];
            for (int i = 0; i < 4; i++) {
                af[i] = *(const s16x8*)&As[(wm * 64 + i * 16 + c15) * 72 + kk * 32 + g * 8];
                bf[i] = *(const s16x8*)&Bs[(wn * 64 + i * 16 + c15) * 72 + kk * 32 + g * 8];
            }
            for (int mi = 0; mi < 4; mi++)
                for (int ni = 0; ni < 4; ni++)
                    acc[mi][ni] = __builtin_amdgcn_mfma_f32_16x16x32_bf16(
                        af[mi], bf[ni], acc[mi][ni], 0, 0, 0);
        }
    }

    for (int mi = 0; mi < 4; mi++) {
        int r = m0 + wm * 64 + mi * 16 + g * 4;
        int batch = r >> 11, nbase = r & 2047;
        for (int ni = 0; ni < 4; ni++) {
            int cN = n0 + wn * 64 + ni * 16 + c15;
            int p = cN >> 8, h = (cN >> 6) & 3, d = cN & 63;
            size_t hb = (size_t)((branch * 4 + batch) * 4 + h) * 131072;
            f32x4 v = acc[mi][ni];
            if (p == 2) {
                s16x4 pk;
                for (int rg = 0; rg < 4; rg++) pk[rg] = (short)f2b(v[rg]);
                int pos = nbase & 31;
                int slot = ((pos & 15) >> 2) * 8 + ((pos >> 4) << 2);
                *(s16x4*)(Vt + hb + (size_t)d * 2048 + (nbase & ~31) + slot) = pk;
            } else if (p == 0) {
                for (int rg = 0; rg < 4; rg++)
                    Qo[hb + (size_t)(nbase + rg) * 64 + d] = f2b(v[rg] * QSCALE);
            } else {
                for (int rg = 0; rg < 4; rg++)
                    Ko[hb + (size_t)(nbase + rg) * 64 + d] = f2b(v[rg]);
            }
        }
    }
}

// ---------------- flash attention, fixed-max streaming softmax ----------------
// One wave = 32 q-rows of one (branch,b,h). 32 kpos/iter, A/B register prefetch.
#define LOADKV(KF, VF, T) do {                                            \
    const u16* _kb = kbase + (size_t)(T) * 2048;                          \
    KF[0][0] = *(const s16x8*)(_kb);                                      \
    KF[0][1] = *(const s16x8*)(_kb + 32);                                 \
    KF[1][0] = *(const s16x8*)(_kb + 1024);                               \
    KF[1][1] = *(const s16x8*)(_kb + 1056);                               \
    const u16* _vb = vbase + (T) * 32;                                    \
    VF[0] = *(const s16x8*)(_vb);                                         \
    VF[1] = *(const s16x8*)(_vb + 32768);                                 \
    VF[2] = *(const s16x8*)(_vb + 65536);                                 \
    VF[3] = *(const s16x8*)(_vb + 98304);                                 \
} while (0)

#define ATTN_STEP(KF, VF) do {                                                              \
    _Pragma("unroll")                                                                       \
    for (int s = 0; s < 2; s++) {                                                           \
        f32x4 sa0 = __builtin_amdgcn_mfma_f32_16x16x32_bf16(KF[0][0], qf[s][0], z4, 0, 0, 0); \
        sa0 = __builtin_amdgcn_mfma_f32_16x16x32_bf16(KF[0][1], qf[s][1], sa0, 0, 0, 0);    \
        f32x4 sa1 = __builtin_amdgcn_mfma_f32_16x16x32_bf16(KF[1][0], qf[s][0], z4, 0, 0, 0); \
        sa1 = __builtin_amdgcn_mfma_f32_16x16x32_bf16(KF[1][1], qf[s][1], sa1, 0, 0, 0);    \
        float q0 = fexp2(sa0[0]), q1 = fexp2(sa0[1]);                                       \
        float q2 = fexp2(sa0[2]), q3 = fexp2(sa0[3]);                                       \
        float q4 = fexp2(sa1[0]), q5 = fexp2(sa1[1]);                                       \
        float q6 = fexp2(sa1[2]), q7 = fexp2(sa1[3]);                                       \
        lsp[s] += ((q0 + q1) + (q2 + q3)) + ((q4 + q5) + (q6 + q7));                        \
        u32x4 pw;                                                                           \
        pw[0] = cvtpk(q0, q1); pw[1] = cvtpk(q2, q3);                                       \
        pw[2] = cvtpk(q4, q5); pw[3] = cvtpk(q6, q7);                                       \
        union { u32x4 w; s16x8 h; } pu; pu.w = pw;                                          \
        s16x8 pb = pu.h;                                                                    \
        _Pragma("unroll")                                                                   \
        for (int dt = 0; dt < 4; dt++)                                                      \
            oac[s][dt] = __builtin_amdgcn_mfma_f32_16x16x32_bf16(VF[dt], pb, oac[s][dt], 0, 0, 0); \
    }                                                                                       \
} while (0)

__global__ __launch_bounds__(256) void attn_kernel(const u16* __restrict__ Qg,
                                                   const u16* __restrict__ Kg,
                                                   const u16* __restrict__ Vg,
                                                   u16* __restrict__ Og) {
    int wid = (int)((blockIdx.x * 256 + threadIdx.x) >> 6);
    int lane = threadIdx.x & 63;
    int inst = wid >> 6;   // 48 instances
    int qt = wid & 63;     // 64 q-tiles of 32 rows
    int g = lane >> 4, c = lane & 15;
    const u16* Qh = Qg + (size_t)inst * 131072;
    const u16* Kh = Kg + (size_t)inst * 131072;
    const u16* Vh = Vg + (size_t)inst * 131072;

    f32x4 z4 = {0.f, 0.f, 0.f, 0.f};
    s16x8 qf[2][2];
    #pragma unroll
    for (int s = 0; s < 2; s++)
        #pragma unroll
        for (int kk = 0; kk < 2; kk++)
            qf[s][kk] = *(const s16x8*)(Qh + (size_t)(qt * 32 + s * 16 + c) * 64 + kk * 32 + g * 8);

    f32x4 oac[2][4];
    #pragma unroll
    for (int s = 0; s < 2; s++)
        #pragma unroll
        for (int dt = 0; dt < 4; dt++) oac[s][dt] = z4;
    float lsp[2] = {0.f, 0.f};

    const u16* kbase = Kh + c * 64 + g * 8;
    const u16* vbase = Vh + (size_t)c * 2048 + g * 8;

    s16x8 kfA[2][2], vfA[4], kfB[2][2], vfB[4];
    LOADKV(kfA, vfA, 0);
    for (int kt = 0; kt < 64; kt += 2) {
        LOADKV(kfB, vfB, kt + 1);
        ATTN_STEP(kfA, vfA);
        if (kt + 2 < 64) LOADKV(kfA, vfA, kt + 2);
        ATTN_STEP(kfB, vfB);
    }

    int branch = inst >> 4, batch = (inst >> 2) & 3, h = inst & 3;
    #pragma unroll
    for (int s = 0; s < 2; s++) {
        float ls = lsp[s];
        ls += __shfl_xor(ls, 16);
        ls += __shfl_xor(ls, 32);
        float inv = 1.0f / ls;
        int n = qt * 32 + s * 16 + c;
        u16* dst = Og + ((size_t)(branch * 4 + batch) * 2048 + n) * 256 + h * 64;
        #pragma unroll
        for (int dt = 0; dt < 4; dt++) {
            s16x4 ob;
            for (int rg = 0; rg < 4; rg++) ob[rg] = (short)f2b(oac[s][dt][rg] * inv);
            *(s16x4*)(dst + dt * 16 + g * 4) = ob;
        }
    }
}

// ---------------- proj GEMM: O_b[8192][256] @ Wp_t + bp, select by idx, dual f32 write ----------------
__global__ __launch_bounds__(256) void proj_gemm_kernel(const u16* __restrict__ Oall,
                                                        const u16* __restrict__ Wpt_all,
                                                        const int* __restrict__ idx,
                                                        const float* __restrict__ bp1,
                                                        const float* __restrict__ bp2,
                                                        const float* __restrict__ bp3,
                                                        float* __restrict__ out) {
    __shared__ u16 As[128 * 72];
    __shared__ u16 Bs[128 * 72];
    const int tid = threadIdx.x;
    const int lane = tid & 63, w = tid >> 6, wm = w >> 1, wn = w & 1;
    const int g = lane >> 4, c15 = lane & 15;
    const int branch = blockIdx.z;
    const int m0 = blockIdx.y * 128, n0 = blockIdx.x * 128;
    const u16* A = Oall + (size_t)branch * 8192 * 256;
    const u16* Bt = Wpt_all + (size_t)branch * 196608;
    const float* bp = (branch == 0) ? bp1 : ((branch == 1) ? bp2 : bp3);
    const int Kdim = 256, lda = 256, ldb = 256;

    f32x4 z4 = {0.f, 0.f, 0.f, 0.f};
    f32x4 acc[4][4];
    for (int mi = 0; mi < 4; mi++)
        for (int ni = 0; ni < 4; ni++) acc[mi][ni] = z4;

    for (int k0 = 0; k0 < Kdim; k0 += 64) {
        __syncthreads();
        for (int cidx = 0; cidx < 4; cidx++) {
            int i = cidx * 256 + tid;
            int row = i >> 3, cb = i & 7;
            *(s16x8*)&As[row * 72 + cb * 8] =
                *(const s16x8*)(A + (size_t)(m0 + row) * lda + k0 + cb * 8);
            *(s16x8*)&Bs[row * 72 + cb * 8] =
                *(const s16x8*)(Bt + (size_t)(n0 + row) * ldb + k0 + cb * 8);
        }
        __syncthreads();
        for (int kk = 0; kk < 2; kk++) {
            s16x8 af[4], bf[4];
            for (int i = 0; i < 4; i++) {
                af[i] = *(const s16x8*)&As[(wm * 64 + i * 16 + c15) * 72 + kk * 32 + g * 8];
                bf[i] = *(const s16x8*)&Bs[(wn * 64 + i * 16 + c15) * 72 + kk * 32 + g * 8];
            }
            for (int mi = 0; mi < 4; mi++)
                for (int ni = 0; ni < 4; ni++)
                    acc[mi][ni] = __builtin_amdgcn_mfma_f32_16x16x32_bf16(
                        af[mi], bf[ni], acc[mi][ni], 0, 0, 0);
        }
    }

    for (int mi = 0; mi < 4; mi++) {
        int r = m0 + wm * 64 + mi * 16 + g * 4;
        for (int ni = 0; ni < 4; ni++) {
            int cN = n0 + wn * 64 + ni * 16 + c15;
            float bj = bp[cN];
            f32x4 v = acc[mi][ni];
            for (int rg = 0; rg < 4; rg++) {
                int t = r + rg;
                if (idx[t] == branch) {
                    float wv = v[rg] + bj;
                    out[(size_t)t * 768 + cN] = wv;                 // xo
                    out[6291456u + (size_t)t * 768 + cN] = wv;      // xd
                }
            }
        }
    }
}

extern "C" void kernel_launch(void* const* d_in, const int* in_sizes, int n_in,
                              void* d_out, int out_size, void* d_ws, size_t ws_size,
                              hipStream_t stream) {
    const float* x   = (const float*)d_in[0];
    const float* Wq1 = (const float*)d_in[1];
    const float* Wq2 = (const float*)d_in[2];
    const float* Wq3 = (const float*)d_in[3];
    const float* Wp1 = (const float*)d_in[4];
    const float* bp1 = (const float*)d_in[5];
    const float* Wp2 = (const float*)d_in[6];
    const float* bp2 = (const float*)d_in[7];
    const float* Wp3 = (const float*)d_in[8];
    const float* bp3 = (const float*)d_in[9];
    const float* Wg  = (const float*)d_in[10];
    float* out = (float*)d_out;

    char* ws = (char*)d_ws;
    u16* xb  = (u16*)(ws + 0);          // 12582912 B
    u16* wqt = (u16*)(ws + 12582912);   // 3538944 B
    u16* wpt = (u16*)(ws + 16121856);   // 1179648 B
    u16* Qb  = (u16*)(ws + 17301504);   // 12582912 B (48 x [2048][64], pre-scaled)
    u16* Kb  = (u16*)(ws + 29884416);   // 12582912 B
    u16* Vtb = (u16*)(ws + 42467328);   // 12582912 B (48 x [64][2048], slot-remapped)
    u16* Ob  = (u16*)(ws + 55050240);   // 12582912 B (3 x [8192][256])
    int* idx = (int*)(ws + 67633152);   // 32768 B

    cast_x_kernel<<<3072, 256, 0, stream>>>(x, xb);
    wcast_kernel<<<2304, 256, 0, stream>>>(Wq1, wqt + 0 * 589824, 768, 768);
    wcast_kernel<<<2304, 256, 0, stream>>>(Wq2, wqt + 1 * 589824, 768, 768);
    wcast_kernel<<<2304, 256, 0, stream>>>(Wq3, wqt + 2 * 589824, 768, 768);
    wcast_kernel<<<768, 256, 0, stream>>>(Wp1, wpt + 0 * 196608, 256, 768);
    wcast_kernel<<<768, 256, 0, stream>>>(Wp2, wpt + 1 * 196608, 256, 768);
    wcast_kernel<<<768, 256, 0, stream>>>(Wp3, wpt + 2 * 196608, 256, 768);
    gate_kernel<<<2048, 256, 0, stream>>>(x, Wg, idx, out);
    qkv_gemm_kernel<<<dim3(6, 64, 3), 256, 0, stream>>>(xb, wqt, Qb, Kb, Vtb);
    attn_kernel<<<768, 256, 0, stream>>>(Qb, Kb, Vtb, Ob);
    proj_gemm_kernel<<<dim3(6, 64, 3), 256, 0, stream>>>(Ob, wpt, idx, bp1, bp2, bp3, out);
}

// Round 4
// 296.236 us; speedup vs baseline: 1.3184x; 1.0406x over previous
//
#include <hip/hip_runtime.h>

typedef short s16x4 __attribute__((ext_vector_type(4)));
typedef short s16x8 __attribute__((ext_vector_type(8)));
typedef float f32x4 __attribute__((ext_vector_type(4)));
typedef unsigned u32x4 __attribute__((ext_vector_type(4)));
typedef unsigned short u16;

__device__ __forceinline__ u16 f2b(float f) {
    union { float f; unsigned u; } v; v.f = f;
    unsigned r = v.u + 0x7FFFu + ((v.u >> 16) & 1u);
    return (u16)(r >> 16);
}

__device__ __forceinline__ float fexp2(float x) {
    float r; asm("v_exp_f32 %0, %1" : "=v"(r) : "v"(x)); return r;
}

__device__ __forceinline__ unsigned cvtpk(float lo, float hi) {
    unsigned r; asm("v_cvt_pk_bf16_f32 %0, %1, %2" : "=v"(r) : "v"(lo), "v"(hi)); return r;
}

// Q pre-scale: hd^-0.5 * log2(e) so attention uses v_exp_f32 (2^x) directly
#define QSCALE 0.1803368801111244f

// ---------------- cast x (fp32) -> bf16 ----------------
__global__ __launch_bounds__(256) void cast_x_kernel(const float* __restrict__ x,
                                                     u16* __restrict__ xb) {
    size_t i = ((size_t)blockIdx.x * 256 + threadIdx.x) * 8;
    const f32x4* s = (const f32x4*)(x + i);
    f32x4 a = s[0], b = s[1];
    s16x8 o;
    o[0] = (short)f2b(a[0]); o[1] = (short)f2b(a[1]);
    o[2] = (short)f2b(a[2]); o[3] = (short)f2b(a[3]);
    o[4] = (short)f2b(b[0]); o[5] = (short)f2b(b[1]);
    o[6] = (short)f2b(b[2]); o[7] = (short)f2b(b[3]);
    *(s16x8*)(xb + i) = o;
}

// ------------- transpose + cast all 6 weights in one launch -------------
// y in [0,3): Wqkv[y] 768x768 -> wqt + y*589824 ; y in [3,6): Wp[y-3] 256x768 -> wpt + (y-3)*196608
__global__ __launch_bounds__(256) void wcast_all_kernel(const float* __restrict__ W0,
                                                        const float* __restrict__ W1,
                                                        const float* __restrict__ W2,
                                                        const float* __restrict__ W3,
                                                        const float* __restrict__ W4,
                                                        const float* __restrict__ W5,
                                                        u16* __restrict__ wqt,
                                                        u16* __restrict__ wpt) {
    int y = blockIdx.y;
    int gid = blockIdx.x * 256 + threadIdx.x;
    const float* W; u16* dst; int K;
    if (y < 3) { W = (y == 0) ? W0 : (y == 1) ? W1 : W2; dst = wqt + y * 589824; K = 768;
                 if (gid >= 589824) return; }
    else       { W = (y == 3) ? W3 : (y == 4) ? W4 : W5; dst = wpt + (y - 3) * 196608; K = 256;
                 if (gid >= 196608) return; }
    int n = gid / K, k = gid - n * K;
    dst[gid] = f2b(W[(size_t)k * 768 + n]);
}

// ---------------- gate: idx = argmax(x @ Wg) ----------------
__global__ __launch_bounds__(256) void gate_kernel(const float* __restrict__ x,
                                                   const float* __restrict__ Wg,
                                                   int* __restrict__ idx,
                                                   float* __restrict__ out) {
    int t = blockIdx.x * 4 + (threadIdx.x >> 6);
    int lane = threadIdx.x & 63;
    const float* xr = x + (size_t)t * 768;
    float z0 = 0.f, z1 = 0.f, z2 = 0.f;
    for (int c = lane; c < 768; c += 64) {
        float xv = xr[c];
        z0 = fmaf(xv, Wg[c * 3 + 0], z0);
        z1 = fmaf(xv, Wg[c * 3 + 1], z1);
        z2 = fmaf(xv, Wg[c * 3 + 2], z2);
    }
    for (int o = 32; o; o >>= 1) {
        z0 += __shfl_xor(z0, o);
        z1 += __shfl_xor(z1, o);
        z2 += __shfl_xor(z2, o);
    }
    if (lane == 0) {
        int k = 0; float b = z0;
        if (z1 > b) { b = z1; k = 1; }
        if (z2 > b) { b = z2; k = 2; }
        idx[t] = k;
        out[12582912 + t] = (float)k;   // idx output
    }
}

// ---------------- QKV GEMM: xb[8192][768] @ Wqkv_t -> Q/K/V scatter ----------------
__global__ __launch_bounds__(256) void qkv_gemm_kernel(const u16* __restrict__ A,
                                                       const u16* __restrict__ Bt_all,
                                                       u16* __restrict__ Qo,
                                                       u16* __restrict__ Ko,
                                                       u16* __restrict__ Vt) {
    __shared__ u16 As[128 * 72];
    __shared__ u16 Bs[128 * 72];
    const int tid = threadIdx.x;
    const int lane = tid & 63, w = tid >> 6, wm = w >> 1, wn = w & 1;
    const int g = lane >> 4, c15 = lane & 15;
    const int branch = blockIdx.z;
    const int m0 = blockIdx.y * 128, n0 = blockIdx.x * 128;
    const u16* Bt = Bt_all + (size_t)branch * 589824;
    const int Kdim = 768, lda = 768, ldb = 768;

    f32x4 z4 = {0.f, 0.f, 0.f, 0.f};
    f32x4 acc[4][4];
    for (int mi = 0; mi < 4; mi++)
        for (int ni = 0; ni < 4; ni++) acc[mi][ni] = z4;

    for (int k0 = 0; k0 < Kdim; k0 += 64) {
        __syncthreads();
        for (int cidx = 0; cidx < 4; cidx++) {
            int i = cidx * 256 + tid;
            int row = i >> 3, cb = i & 7;
            *(s16x8*)&As[row * 72 + cb * 8] =
                *(const s16x8*)(A + (size_t)(m0 + row) * lda + k0 + cb * 8);
            *(s16x8*)&Bs[row * 72 + cb * 8] =
                *(const s16x8*)(Bt + (size_t)(n0 + row) * ldb + k0 + cb * 8);
        }
        __syncthreads();
        for (int kk = 0; kk < 2; kk++) {
            s16x8 af[4], bf[4];
            for (int i = 0; i < 4; i++) {
                af[i] = *(const s16x8*)&As[(wm * 64 + i * 16 + c15) * 72 + kk * 32 + g * 8];
                bf[i] = *(const s16x8*)&Bs[(wn * 64 + i * 16 + c15) * 72 + kk * 32 + g * 8];
            }
            for (int mi = 0; mi < 4; mi++)
                for (int ni = 0; ni < 4; ni++)
                    acc[mi][ni] = __builtin_amdgcn_mfma_f32_16x16x32_bf16(
                        af[mi], bf[ni], acc[mi][ni], 0, 0, 0);
        }
    }

    for (int mi = 0; mi < 4; mi++) {
        int r = m0 + wm * 64 + mi * 16 + g * 4;
        int batch = r >> 11, nbase = r & 2047;
        for (int ni = 0; ni < 4; ni++) {
            int cN = n0 + wn * 64 + ni * 16 + c15;
            int p = cN >> 8, h = (cN >> 6) & 3, d = cN & 63;
            size_t hb = (size_t)((branch * 4 + batch) * 4 + h) * 131072;
            f32x4 v = acc[mi][ni];
            if (p == 2) {
                s16x4 pk;
                for (int rg = 0; rg < 4; rg++) pk[rg] = (short)f2b(v[rg]);
                int pos = nbase & 31;
                int slot = ((pos & 15) >> 2) * 8 + ((pos >> 4) << 2);
                *(s16x4*)(Vt + hb + (size_t)d * 2048 + (nbase & ~31) + slot) = pk;
            } else if (p == 0) {
                for (int rg = 0; rg < 4; rg++)
                    Qo[hb + (size_t)(nbase + rg) * 64 + d] = f2b(v[rg] * QSCALE);
            } else {
                for (int rg = 0; rg < 4; rg++)
                    Ko[hb + (size_t)(nbase + rg) * 64 + d] = f2b(v[rg]);
            }
        }
    }
}

// ---------------- flash attention, fixed-max streaming softmax, k-split ----------------
// Block = 4 waves: (qt parity, k-half). Each wave: 32 q-rows x 1024 kpos.
// Partials combine by pure addition (fixed max) through LDS.
#define LOADKV(KF, VF, T) do {                                            \
    const u16* _kb = kbase + (size_t)(T) * 2048;                          \
    KF[0][0] = *(const s16x8*)(_kb);                                      \
    KF[0][1] = *(const s16x8*)(_kb + 32);                                 \
    KF[1][0] = *(const s16x8*)(_kb + 1024);                               \
    KF[1][1] = *(const s16x8*)(_kb + 1056);                               \
    const u16* _vb = vbase + (T) * 32;                                    \
    VF[0] = *(const s16x8*)(_vb);                                         \
    VF[1] = *(const s16x8*)(_vb + 32768);                                 \
    VF[2] = *(const s16x8*)(_vb + 65536);                                 \
    VF[3] = *(const s16x8*)(_vb + 98304);                                 \
} while (0)

#define ATTN_STEP(KF, VF) do {                                                              \
    _Pragma("unroll")                                                                       \
    for (int s = 0; s < 2; s++) {                                                           \
        f32x4 sa0 = __builtin_amdgcn_mfma_f32_16x16x32_bf16(KF[0][0], qf[s][0], z4, 0, 0, 0); \
        sa0 = __builtin_amdgcn_mfma_f32_16x16x32_bf16(KF[0][1], qf[s][1], sa0, 0, 0, 0);    \
        f32x4 sa1 = __builtin_amdgcn_mfma_f32_16x16x32_bf16(KF[1][0], qf[s][0], z4, 0, 0, 0); \
        sa1 = __builtin_amdgcn_mfma_f32_16x16x32_bf16(KF[1][1], qf[s][1], sa1, 0, 0, 0);    \
        float q0 = fexp2(sa0[0]), q1 = fexp2(sa0[1]);                                       \
        float q2 = fexp2(sa0[2]), q3 = fexp2(sa0[3]);                                       \
        float q4 = fexp2(sa1[0]), q5 = fexp2(sa1[1]);                                       \
        float q6 = fexp2(sa1[2]), q7 = fexp2(sa1[3]);                                       \
        lsp[s] += ((q0 + q1) + (q2 + q3)) + ((q4 + q5) + (q6 + q7));                        \
        u32x4 pw;                                                                           \
        pw[0] = cvtpk(q0, q1); pw[1] = cvtpk(q2, q3);                                       \
        pw[2] = cvtpk(q4, q5); pw[3] = cvtpk(q6, q7);                                       \
        union { u32x4 w; s16x8 h; } pu; pu.w = pw;                                          \
        s16x8 pb = pu.h;                                                                    \
        _Pragma("unroll")                                                                   \
        for (int dt = 0; dt < 4; dt++)                                                      \
            oac[s][dt] = __builtin_amdgcn_mfma_f32_16x16x32_bf16(VF[dt], pb, oac[s][dt], 0, 0, 0); \
    }                                                                                       \
} while (0)

__global__ __launch_bounds__(256) void attn_kernel(const u16* __restrict__ Qg,
                                                   const u16* __restrict__ Kg,
                                                   const u16* __restrict__ Vg,
                                                   u16* __restrict__ Og) {
    __shared__ float comb[2][64][34];
    const int tid = threadIdx.x;
    const int w = tid >> 6, lane = tid & 63;
    const int inst = blockIdx.x >> 5;      // 48 instances
    const int qp = blockIdx.x & 31;        // 32 q-pairs
    const int qt = qp * 2 + (w & 1);       // q-tile of 32 rows
    const int kh = w >> 1;                 // k-half
    const int g = lane >> 4, c = lane & 15;
    const u16* Qh = Qg + (size_t)inst * 131072;

    f32x4 z4 = {0.f, 0.f, 0.f, 0.f};
    s16x8 qf[2][2];
    #pragma unroll
    for (int s = 0; s < 2; s++)
        #pragma unroll
        for (int kk = 0; kk < 2; kk++)
            qf[s][kk] = *(const s16x8*)(Qh + (size_t)(qt * 32 + s * 16 + c) * 64 + kk * 32 + g * 8);

    f32x4 oac[2][4];
    #pragma unroll
    for (int s = 0; s < 2; s++)
        #pragma unroll
        for (int dt = 0; dt < 4; dt++) oac[s][dt] = z4;
    float lsp[2] = {0.f, 0.f};

    const u16* kbase = Kg + (size_t)inst * 131072 + kh * 65536 + c * 64 + g * 8;
    const u16* vbase = Vg + (size_t)inst * 131072 + (size_t)c * 2048 + kh * 1024 + g * 8;

    s16x8 kfA[2][2], vfA[4], kfB[2][2], vfB[4];
    LOADKV(kfA, vfA, 0);
    for (int kt = 0; kt < 32; kt += 2) {
        LOADKV(kfB, vfB, kt + 1);
        ATTN_STEP(kfA, vfA);
        if (kt + 2 < 32) LOADKV(kfA, vfA, kt + 2);
        ATTN_STEP(kfB, vfB);
    }

    // combine the two k-halves (fixed-max: pure addition)
    if (w >= 2) {
        int wi = w - 2;
        #pragma unroll
        for (int s = 0; s < 2; s++) {
            #pragma unroll
            for (int dt = 0; dt < 4; dt++)
                *(f32x4*)&comb[wi][lane][s * 16 + dt * 4] = oac[s][dt];
            comb[wi][lane][32 + s] = lsp[s];
        }
    }
    __syncthreads();
    if (w < 2) {
        int branch = inst >> 4, batch = (inst >> 2) & 3, h = inst & 3;
        #pragma unroll
        for (int s = 0; s < 2; s++) {
            #pragma unroll
            for (int dt = 0; dt < 4; dt++) {
                f32x4 o2 = *(const f32x4*)&comb[w][lane][s * 16 + dt * 4];
                oac[s][dt] = oac[s][dt] + o2;
            }
            float ls = lsp[s] + comb[w][lane][32 + s];
            ls += __shfl_xor(ls, 16);
            ls += __shfl_xor(ls, 32);
            float inv = 1.0f / ls;
            int n = qt * 32 + s * 16 + c;
            u16* dst = Og + ((size_t)(branch * 4 + batch) * 2048 + n) * 256 + h * 64;
            #pragma unroll
            for (int dt = 0; dt < 4; dt++) {
                s16x4 ob;
                for (int rg = 0; rg < 4; rg++) ob[rg] = (short)f2b(oac[s][dt][rg] * inv);
                *(s16x4*)(dst + dt * 16 + g * 4) = ob;
            }
        }
    }
}

// ---------------- proj GEMM: O_b[8192][256] @ Wp_t + bp, select by idx, dual f32 write ----------------
__global__ __launch_bounds__(256) void proj_gemm_kernel(const u16* __restrict__ Oall,
                                                        const u16* __restrict__ Wpt_all,
                                                        const int* __restrict__ idx,
                                                        const float* __restrict__ bp1,
                                                        const float* __restrict__ bp2,
                                                        const float* __restrict__ bp3,
                                                        float* __restrict__ out) {
    __shared__ u16 As[128 * 72];
    __shared__ u16 Bs[128 * 72];
    const int tid = threadIdx.x;
    const int lane = tid & 63, w = tid >> 6, wm = w >> 1, wn = w & 1;
    const int g = lane >> 4, c15 = lane & 15;
    const int branch = blockIdx.z;
    const int m0 = blockIdx.y * 128, n0 = blockIdx.x * 128;
    const u16* A = Oall + (size_t)branch * 8192 * 256;
    const u16* Bt = Wpt_all + (size_t)branch * 196608;
    const float* bp = (branch == 0) ? bp1 : ((branch == 1) ? bp2 : bp3);
    const int Kdim = 256, lda = 256, ldb = 256;

    f32x4 z4 = {0.f, 0.f, 0.f, 0.f};
    f32x4 acc[4][4];
    for (int mi = 0; mi < 4; mi++)
        for (int ni = 0; ni < 4; ni++) acc[mi][ni] = z4;

    for (int k0 = 0; k0 < Kdim; k0 += 64) {
        __syncthreads();
        for (int cidx = 0; cidx < 4; cidx++) {
            int i = cidx * 256 + tid;
            int row = i >> 3, cb = i & 7;
            *(s16x8*)&As[row * 72 + cb * 8] =
                *(const s16x8*)(A + (size_t)(m0 + row) * lda + k0 + cb * 8);
            *(s16x8*)&Bs[row * 72 + cb * 8] =
                *(const s16x8*)(Bt + (size_t)(n0 + row) * ldb + k0 + cb * 8);
        }
        __syncthreads();
        for (int kk = 0; kk < 2; kk++) {
            s16x8 af[4], bf[4];
            for (int i = 0; i < 4; i++) {
                af[i] = *(const s16x8*)&As[(wm * 64 + i * 16 + c15) * 72 + kk * 32 + g * 8];
                bf[i] = *(const s16x8*)&Bs[(wn * 64 + i * 16 + c15) * 72 + kk * 32 + g * 8];
            }
            for (int mi = 0; mi < 4; mi++)
                for (int ni = 0; ni < 4; ni++)
                    acc[mi][ni] = __builtin_amdgcn_mfma_f32_16x16x32_bf16(
                        af[mi], bf[ni], acc[mi][ni], 0, 0, 0);
        }
    }

    for (int mi = 0; mi < 4; mi++) {
        int r = m0 + wm * 64 + mi * 16 + g * 4;
        for (int ni = 0; ni < 4; ni++) {
            int cN = n0 + wn * 64 + ni * 16 + c15;
            float bj = bp[cN];
            f32x4 v = acc[mi][ni];
            for (int rg = 0; rg < 4; rg++) {
                int t = r + rg;
                if (idx[t] == branch) {
                    float wv = v[rg] + bj;
                    out[(size_t)t * 768 + cN] = wv;                 // xo
                    out[6291456u + (size_t)t * 768 + cN] = wv;      // xd
                }
            }
        }
    }
}

extern "C" void kernel_launch(void* const* d_in, const int* in_sizes, int n_in,
                              void* d_out, int out_size, void* d_ws, size_t ws_size,
                              hipStream_t stream) {
    const float* x   = (const float*)d_in[0];
    const float* Wq1 = (const float*)d_in[1];
    const float* Wq2 = (const float*)d_in[2];
    const float* Wq3 = (const float*)d_in[3];
    const float* Wp1 = (const float*)d_in[4];
    const float* bp1 = (const float*)d_in[5];
    const float* Wp2 = (const float*)d_in[6];
    const float* bp2 = (const float*)d_in[7];
    const float* Wp3 = (const float*)d_in[8];
    const float* bp3 = (const float*)d_in[9];
    const float* Wg  = (const float*)d_in[10];
    float* out = (float*)d_out;

    char* ws = (char*)d_ws;
    u16* xb  = (u16*)(ws + 0);          // 12582912 B
    u16* wqt = (u16*)(ws + 12582912);   // 3538944 B
    u16* wpt = (u16*)(ws + 16121856);   // 1179648 B
    u16* Qb  = (u16*)(ws + 17301504);   // 12582912 B (48 x [2048][64], pre-scaled)
    u16* Kb  = (u16*)(ws + 29884416);   // 12582912 B
    u16* Vtb = (u16*)(ws + 42467328);   // 12582912 B (48 x [64][2048], slot-remapped)
    u16* Ob  = (u16*)(ws + 55050240);   // 12582912 B (3 x [8192][256])
    int* idx = (int*)(ws + 67633152);   // 32768 B

    cast_x_kernel<<<3072, 256, 0, stream>>>(x, xb);
    wcast_all_kernel<<<dim3(2304, 6), 256, 0, stream>>>(Wq1, Wq2, Wq3, Wp1, Wp2, Wp3, wqt, wpt);
    gate_kernel<<<2048, 256, 0, stream>>>(x, Wg, idx, out);
    qkv_gemm_kernel<<<dim3(6, 64, 3), 256, 0, stream>>>(xb, wqt, Qb, Kb, Vtb);
    attn_kernel<<<1536, 256, 0, stream>>>(Qb, Kb, Vtb, Ob);
    proj_gemm_kernel<<<dim3(6, 64, 3), 256, 0, stream>>>(Ob, wpt, idx, bp1, bp2, bp3, out);
}

// Round 5
// 296.089 us; speedup vs baseline: 1.3190x; 1.0005x over previous
//
#include <hip/hip_runtime.h>

typedef short s16x4 __attribute__((ext_vector_type(4)));
typedef short s16x8 __attribute__((ext_vector_type(8)));
typedef float f32x4 __attribute__((ext_vector_type(4)));
typedef unsigned u32x4 __attribute__((ext_vector_type(4)));
typedef unsigned short u16;

__device__ __forceinline__ u16 f2b(float f) {
    union { float f; unsigned u; } v; v.f = f;
    unsigned r = v.u + 0x7FFFu + ((v.u >> 16) & 1u);
    return (u16)(r >> 16);
}

__device__ __forceinline__ float fexp2(float x) {
    float r; asm("v_exp_f32 %0, %1" : "=v"(r) : "v"(x)); return r;
}

__device__ __forceinline__ unsigned cvtpk(float lo, float hi) {
    unsigned r; asm("v_cvt_pk_bf16_f32 %0, %1, %2" : "=v"(r) : "v"(lo), "v"(hi)); return r;
}

// Q pre-scale: hd^-0.5 * log2(e) so attention uses v_exp_f32 (2^x) directly
#define QSCALE 0.1803368801111244f

// ---------------- cast x (fp32) -> bf16 ----------------
__global__ __launch_bounds__(256) void cast_x_kernel(const float* __restrict__ x,
                                                     u16* __restrict__ xb) {
    size_t i = ((size_t)blockIdx.x * 256 + threadIdx.x) * 8;
    const f32x4* s = (const f32x4*)(x + i);
    f32x4 a = s[0], b = s[1];
    s16x8 o;
    o[0] = (short)f2b(a[0]); o[1] = (short)f2b(a[1]);
    o[2] = (short)f2b(a[2]); o[3] = (short)f2b(a[3]);
    o[4] = (short)f2b(b[0]); o[5] = (short)f2b(b[1]);
    o[6] = (short)f2b(b[2]); o[7] = (short)f2b(b[3]);
    *(s16x8*)(xb + i) = o;
}

// ------------- transpose + cast all 6 weights in one launch -------------
__global__ __launch_bounds__(256) void wcast_all_kernel(const float* __restrict__ W0,
                                                        const float* __restrict__ W1,
                                                        const float* __restrict__ W2,
                                                        const float* __restrict__ W3,
                                                        const float* __restrict__ W4,
                                                        const float* __restrict__ W5,
                                                        u16* __restrict__ wqt,
                                                        u16* __restrict__ wpt) {
    int y = blockIdx.y;
    int gid = blockIdx.x * 256 + threadIdx.x;
    const float* W; u16* dst; int K;
    if (y < 3) { W = (y == 0) ? W0 : (y == 1) ? W1 : W2; dst = wqt + y * 589824; K = 768;
                 if (gid >= 589824) return; }
    else       { W = (y == 3) ? W3 : (y == 4) ? W4 : W5; dst = wpt + (y - 3) * 196608; K = 256;
                 if (gid >= 196608) return; }
    int n = gid / K, k = gid - n * K;
    dst[gid] = f2b(W[(size_t)k * 768 + n]);
}

// ---------------- gate: idx = argmax(x @ Wg) ----------------
__global__ __launch_bounds__(256) void gate_kernel(const float* __restrict__ x,
                                                   const float* __restrict__ Wg,
                                                   int* __restrict__ idx,
                                                   float* __restrict__ out) {
    int t = blockIdx.x * 4 + (threadIdx.x >> 6);
    int lane = threadIdx.x & 63;
    const float* xr = x + (size_t)t * 768;
    float z0 = 0.f, z1 = 0.f, z2 = 0.f;
    for (int c = lane; c < 768; c += 64) {
        float xv = xr[c];
        z0 = fmaf(xv, Wg[c * 3 + 0], z0);
        z1 = fmaf(xv, Wg[c * 3 + 1], z1);
        z2 = fmaf(xv, Wg[c * 3 + 2], z2);
    }
    for (int o = 32; o; o >>= 1) {
        z0 += __shfl_xor(z0, o);
        z1 += __shfl_xor(z1, o);
        z2 += __shfl_xor(z2, o);
    }
    if (lane == 0) {
        int k = 0; float b = z0;
        if (z1 > b) { b = z1; k = 1; }
        if (z2 > b) { b = z2; k = 2; }
        idx[t] = k;
        out[12582912 + t] = (float)k;   // idx output
    }
}

// ---------------- QKV GEMM: xb[8192][768] @ Wqkv_t -> Q/K/V scatter ----------------
__global__ __launch_bounds__(256) void qkv_gemm_kernel(const u16* __restrict__ A,
                                                       const u16* __restrict__ Bt_all,
                                                       u16* __restrict__ Qo,
                                                       u16* __restrict__ Ko,
                                                       u16* __restrict__ Vt) {
    __shared__ u16 As[128 * 72];
    __shared__ u16 Bs[128 * 72];
    const int tid = threadIdx.x;
    const int lane = tid & 63, w = tid >> 6, wm = w >> 1, wn = w & 1;
    const int g = lane >> 4, c15 = lane & 15;
    const int branch = blockIdx.z;
    const int m0 = blockIdx.y * 128, n0 = blockIdx.x * 128;
    const u16* Bt = Bt_all + (size_t)branch * 589824;
    const int Kdim = 768, lda = 768, ldb = 768;

    f32x4 z4 = {0.f, 0.f, 0.f, 0.f};
    f32x4 acc[4][4];
    for (int mi = 0; mi < 4; mi++)
        for (int ni = 0; ni < 4; ni++) acc[mi][ni] = z4;

    for (int k0 = 0; k0 < Kdim; k0 += 64) {
        __syncthreads();
        for (int cidx = 0; cidx < 4; cidx++) {
            int i = cidx * 256 + tid;
            int row = i >> 3, cb = i & 7;
            *(s16x8*)&As[row * 72 + cb * 8] =
                *(const s16x8*)(A + (size_t)(m0 + row) * lda + k0 + cb * 8);
            *(s16x8*)&Bs[row * 72 + cb * 8] =
                *(const s16x8*)(Bt + (size_t)(n0 + row) * ldb + k0 + cb * 8);
        }
        __syncthreads();
        for (int kk = 0; kk < 2; kk++) {
            s16x8 af[4], bf[4];
            for (int i = 0; i < 4; i++) {
                af[i] = *(const s16x8*)&As[(wm * 64 + i * 16 + c15) * 72 + kk * 32 + g * 8];
                bf[i] = *(const s16x8*)&Bs[(wn * 64 + i * 16 + c15) * 72 + kk * 32 + g * 8];
            }
            for (int mi = 0; mi < 4; mi++)
                for (int ni = 0; ni < 4; ni++)
                    acc[mi][ni] = __builtin_amdgcn_mfma_f32_16x16x32_bf16(
                        af[mi], bf[ni], acc[mi][ni], 0, 0, 0);
        }
    }

    for (int mi = 0; mi < 4; mi++) {
        int r = m0 + wm * 64 + mi * 16 + g * 4;
        int batch = r >> 11, nbase = r & 2047;
        for (int ni = 0; ni < 4; ni++) {
            int cN = n0 + wn * 64 + ni * 16 + c15;
            int p = cN >> 8, h = (cN >> 6) & 3, d = cN & 63;
            size_t hb = (size_t)((branch * 4 + batch) * 4 + h) * 131072;
            f32x4 v = acc[mi][ni];
            if (p == 2) {
                s16x4 pk;
                for (int rg = 0; rg < 4; rg++) pk[rg] = (short)f2b(v[rg]);
                int pos = nbase & 31;
                int slot = ((pos & 15) >> 2) * 8 + ((pos >> 4) << 2);
                *(s16x4*)(Vt + hb + (size_t)d * 2048 + (nbase & ~31) + slot) = pk;
            } else if (p == 0) {
                for (int rg = 0; rg < 4; rg++)
                    Qo[hb + (size_t)(nbase + rg) * 64 + d] = f2b(v[rg] * QSCALE);
            } else {
                for (int rg = 0; rg < 4; rg++)
                    Ko[hb + (size_t)(nbase + rg) * 64 + d] = f2b(v[rg]);
            }
        }
    }
}

// ---------------- flash attention, fixed-max streaming softmax, XCD-pinned ----------------
// One wave = 32 q-rows x 2048 kpos of one (branch,b,h) instance.
// blockIdx&7 selects the XCD (HW round-robin); all blocks of an instance land
// on one XCD so its 512 KB K/V set stays in that XCD's 4 MB L2 (6 inst x 512 KB = 3 MB).
#define LOADKV(KF, VF, T) do {                                            \
    const u16* _kb = kbase + (size_t)(T) * 2048;                          \
    KF[0][0] = *(const s16x8*)(_kb);                                      \
    KF[0][1] = *(const s16x8*)(_kb + 32);                                 \
    KF[1][0] = *(const s16x8*)(_kb + 1024);                               \
    KF[1][1] = *(const s16x8*)(_kb + 1056);                               \
    const u16* _vb = vbase + (T) * 32;                                    \
    VF[0] = *(const s16x8*)(_vb);                                         \
    VF[1] = *(const s16x8*)(_vb + 32768);                                 \
    VF[2] = *(const s16x8*)(_vb + 65536);                                 \
    VF[3] = *(const s16x8*)(_vb + 98304);                                 \
} while (0)

#define ATTN_STEP(KF, VF) do {                                                              \
    _Pragma("unroll")                                                                       \
    for (int s = 0; s < 2; s++) {                                                           \
        f32x4 sa0 = __builtin_amdgcn_mfma_f32_16x16x32_bf16(KF[0][0], qf[s][0], z4, 0, 0, 0); \
        sa0 = __builtin_amdgcn_mfma_f32_16x16x32_bf16(KF[0][1], qf[s][1], sa0, 0, 0, 0);    \
        f32x4 sa1 = __builtin_amdgcn_mfma_f32_16x16x32_bf16(KF[1][0], qf[s][0], z4, 0, 0, 0); \
        sa1 = __builtin_amdgcn_mfma_f32_16x16x32_bf16(KF[1][1], qf[s][1], sa1, 0, 0, 0);    \
        float q0 = fexp2(sa0[0]), q1 = fexp2(sa0[1]);                                       \
        float q2 = fexp2(sa0[2]), q3 = fexp2(sa0[3]);                                       \
        float q4 = fexp2(sa1[0]), q5 = fexp2(sa1[1]);                                       \
        float q6 = fexp2(sa1[2]), q7 = fexp2(sa1[3]);                                       \
        lsp[s] += ((q0 + q1) + (q2 + q3)) + ((q4 + q5) + (q6 + q7));                        \
        u32x4 pw;                                                                           \
        pw[0] = cvtpk(q0, q1); pw[1] = cvtpk(q2, q3);                                       \
        pw[2] = cvtpk(q4, q5); pw[3] = cvtpk(q6, q7);                                       \
        union { u32x4 w; s16x8 h; } pu; pu.w = pw;                                          \
        s16x8 pb = pu.h;                                                                    \
        _Pragma("unroll")                                                                   \
        for (int dt = 0; dt < 4; dt++)                                                      \
            oac[s][dt] = __builtin_amdgcn_mfma_f32_16x16x32_bf16(VF[dt], pb, oac[s][dt], 0, 0, 0); \
    }                                                                                       \
} while (0)

__global__ __launch_bounds__(256) void attn_kernel(const u16* __restrict__ Qg,
                                                   const u16* __restrict__ Kg,
                                                   const u16* __restrict__ Vg,
                                                   u16* __restrict__ Og) {
    const int b = blockIdx.x;
    const int j = b >> 3;
    const int inst = (b & 7) * 6 + (j % 6);          // XCD-pinned instance
    const int qt = (j / 6) * 4 + (threadIdx.x >> 6); // q-tile of 32 rows
    const int lane = threadIdx.x & 63;
    const int g = lane >> 4, c = lane & 15;
    const u16* Qh = Qg + (size_t)inst * 131072;

    f32x4 z4 = {0.f, 0.f, 0.f, 0.f};
    s16x8 qf[2][2];
    #pragma unroll
    for (int s = 0; s < 2; s++)
        #pragma unroll
        for (int kk = 0; kk < 2; kk++)
            qf[s][kk] = *(const s16x8*)(Qh + (size_t)(qt * 32 + s * 16 + c) * 64 + kk * 32 + g * 8);

    f32x4 oac[2][4];
    #pragma unroll
    for (int s = 0; s < 2; s++)
        #pragma unroll
        for (int dt = 0; dt < 4; dt++) oac[s][dt] = z4;
    float lsp[2] = {0.f, 0.f};

    const u16* kbase = Kg + (size_t)inst * 131072 + c * 64 + g * 8;
    const u16* vbase = Vg + (size_t)inst * 131072 + (size_t)c * 2048 + g * 8;

    s16x8 kfA[2][2], vfA[4], kfB[2][2], vfB[4];
    LOADKV(kfA, vfA, 0);
    for (int kt = 0; kt < 64; kt += 2) {
        LOADKV(kfB, vfB, kt + 1);
        ATTN_STEP(kfA, vfA);
        if (kt + 2 < 64) LOADKV(kfA, vfA, kt + 2);
        ATTN_STEP(kfB, vfB);
    }

    int branch = inst >> 4, batch = (inst >> 2) & 3, h = inst & 3;
    #pragma unroll
    for (int s = 0; s < 2; s++) {
        float ls = lsp[s];
        ls += __shfl_xor(ls, 16);
        ls += __shfl_xor(ls, 32);
        float inv = 1.0f / ls;
        int n = qt * 32 + s * 16 + c;
        u16* dst = Og + ((size_t)(branch * 4 + batch) * 2048 + n) * 256 + h * 64;
        #pragma unroll
        for (int dt = 0; dt < 4; dt++) {
            s16x4 ob;
            for (int rg = 0; rg < 4; rg++) ob[rg] = (short)f2b(oac[s][dt][rg] * inv);
            *(s16x4*)(dst + dt * 16 + g * 4) = ob;
        }
    }
}

// ---------------- proj GEMM: O_b[8192][256] @ Wp_t + bp, select by idx, dual f32 write ----------------
__global__ __launch_bounds__(256) void proj_gemm_kernel(const u16* __restrict__ Oall,
                                                        const u16* __restrict__ Wpt_all,
                                                        const int* __restrict__ idx,
                                                        const float* __restrict__ bp1,
                                                        const float* __restrict__ bp2,
                                                        const float* __restrict__ bp3,
                                                        float* __restrict__ out) {
    __shared__ u16 As[128 * 72];
    __shared__ u16 Bs[128 * 72];
    const int tid = threadIdx.x;
    const int lane = tid & 63, w = tid >> 6, wm = w >> 1, wn = w & 1;
    const int g = lane >> 4, c15 = lane & 15;
    const int branch = blockIdx.z;
    const int m0 = blockIdx.y * 128, n0 = blockIdx.x * 128;
    const u16* A = Oall + (size_t)branch * 8192 * 256;
    const u16* Bt = Wpt_all + (size_t)branch * 196608;
    const float* bp = (branch == 0) ? bp1 : ((branch == 1) ? bp2 : bp3);
    const int Kdim = 256, lda = 256, ldb = 256;

    f32x4 z4 = {0.f, 0.f, 0.f, 0.f};
    f32x4 acc[4][4];
    for (int mi = 0; mi < 4; mi++)
        for (int ni = 0; ni < 4; ni++) acc[mi][ni] = z4;

    for (int k0 = 0; k0 < Kdim; k0 += 64) {
        __syncthreads();
        for (int cidx = 0; cidx < 4; cidx++) {
            int i = cidx * 256 + tid;
            int row = i >> 3, cb = i & 7;
            *(s16x8*)&As[row * 72 + cb * 8] =
                *(const s16x8*)(A + (size_t)(m0 + row) * lda + k0 + cb * 8);
            *(s16x8*)&Bs[row * 72 + cb * 8] =
                *(const s16x8*)(Bt + (size_t)(n0 + row) * ldb + k0 + cb * 8);
        }
        __syncthreads();
        for (int kk = 0; kk < 2; kk++) {
            s16x8 af[4], bf[4];
            for (int i = 0; i < 4; i++) {
                af[i] = *(const s16x8*)&As[(wm * 64 + i * 16 + c15) * 72 + kk * 32 + g * 8];
                bf[i] = *(const s16x8*)&Bs[(wn * 64 + i * 16 + c15) * 72 + kk * 32 + g * 8];
            }
            for (int mi = 0; mi < 4; mi++)
                for (int ni = 0; ni < 4; ni++)
                    acc[mi][ni] = __builtin_amdgcn_mfma_f32_16x16x32_bf16(
                        af[mi], bf[ni], acc[mi][ni], 0, 0, 0);
        }
    }

    for (int mi = 0; mi < 4; mi++) {
        int r = m0 + wm * 64 + mi * 16 + g * 4;
        for (int ni = 0; ni < 4; ni++) {
            int cN = n0 + wn * 64 + ni * 16 + c15;
            float bj = bp[cN];
            f32x4 v = acc[mi][ni];
            for (int rg = 0; rg < 4; rg++) {
                int t = r + rg;
                if (idx[t] == branch) {
                    float wv = v[rg] + bj;
                    out[(size_t)t * 768 + cN] = wv;                 // xo
                    out[6291456u + (size_t)t * 768 + cN] = wv;      // xd
                }
            }
        }
    }
}

extern "C" void kernel_launch(void* const* d_in, const int* in_sizes, int n_in,
                              void* d_out, int out_size, void* d_ws, size_t ws_size,
                              hipStream_t stream) {
    const float* x   = (const float*)d_in[0];
    const float* Wq1 = (const float*)d_in[1];
    const float* Wq2 = (const float*)d_in[2];
    const float* Wq3 = (const float*)d_in[3];
    const float* Wp1 = (const float*)d_in[4];
    const float* bp1 = (const float*)d_in[5];
    const float* Wp2 = (const float*)d_in[6];
    const float* bp2 = (const float*)d_in[7];
    const float* Wp3 = (const float*)d_in[8];
    const float* bp3 = (const float*)d_in[9];
    const float* Wg  = (const float*)d_in[10];
    float* out = (float*)d_out;

    char* ws = (char*)d_ws;
    u16* xb  = (u16*)(ws + 0);          // 12582912 B
    u16* wqt = (u16*)(ws + 12582912);   // 3538944 B
    u16* wpt = (u16*)(ws + 16121856);   // 1179648 B
    u16* Qb  = (u16*)(ws + 17301504);   // 12582912 B (48 x [2048][64], pre-scaled)
    u16* Kb  = (u16*)(ws + 29884416);   // 12582912 B
    u16* Vtb = (u16*)(ws + 42467328);   // 12582912 B (48 x [64][2048], slot-remapped)
    u16* Ob  = (u16*)(ws + 55050240);   // 12582912 B (3 x [8192][256])
    int* idx = (int*)(ws + 67633152);   // 32768 B

    cast_x_kernel<<<3072, 256, 0, stream>>>(x, xb);
    wcast_all_kernel<<<dim3(2304, 6), 256, 0, stream>>>(Wq1, Wq2, Wq3, Wp1, Wp2, Wp3, wqt, wpt);
    gate_kernel<<<2048, 256, 0, stream>>>(x, Wg, idx, out);
    qkv_gemm_kernel<<<dim3(6, 64, 3), 256, 0, stream>>>(xb, wqt, Qb, Kb, Vtb);
    attn_kernel<<<768, 256, 0, stream>>>(Qb, Kb, Vtb, Ob);
    proj_gemm_kernel<<<dim3(6, 64, 3), 256, 0, stream>>>(Ob, wpt, idx, bp1, bp2, bp3, out);
}

// Round 6
// 181.112 us; speedup vs baseline: 2.1564x; 1.6348x over previous
//
#include <hip/hip_runtime.h>

typedef short s16x4 __attribute__((ext_vector_type(4)));
typedef short s16x8 __attribute__((ext_vector_type(8)));
typedef float f32x4 __attribute__((ext_vector_type(4)));
typedef unsigned u32x4 __attribute__((ext_vector_type(4)));
typedef unsigned short u16;

__device__ __forceinline__ u16 f2b(float f) {
    union { float f; unsigned u; } v; v.f = f;
    unsigned r = v.u + 0x7FFFu + ((v.u >> 16) & 1u);
    return (u16)(r >> 16);
}

__device__ __forceinline__ float fexp2(float x) {
    float r; asm("v_exp_f32 %0, %1" : "=v"(r) : "v"(x)); return r;
}

__device__ __forceinline__ unsigned cvtpk(float lo, float hi) {
    unsigned r; asm("v_cvt_pk_bf16_f32 %0, %1, %2" : "=v"(r) : "v"(lo), "v"(hi)); return r;
}

__device__ __forceinline__ void GLL(const void* g, void* l) {
    __builtin_amdgcn_global_load_lds(
        (const __attribute__((address_space(1))) unsigned int*)g,
        (__attribute__((address_space(3))) unsigned int*)l, 16, 0, 0);
}

// Q pre-scale: hd^-0.5 * log2(e) so attention uses v_exp_f32 (2^x) directly
#define QSCALE 0.1803368801111244f

// ---------------- cast x (fp32) -> bf16 ----------------
__global__ __launch_bounds__(256) void cast_x_kernel(const float* __restrict__ x,
                                                     u16* __restrict__ xb) {
    size_t i = ((size_t)blockIdx.x * 256 + threadIdx.x) * 8;
    const f32x4* s = (const f32x4*)(x + i);
    f32x4 a = s[0], b = s[1];
    s16x8 o;
    o[0] = (short)f2b(a[0]); o[1] = (short)f2b(a[1]);
    o[2] = (short)f2b(a[2]); o[3] = (short)f2b(a[3]);
    o[4] = (short)f2b(b[0]); o[5] = (short)f2b(b[1]);
    o[6] = (short)f2b(b[2]); o[7] = (short)f2b(b[3]);
    *(s16x8*)(xb + i) = o;
}

// ------------- transpose + cast all 6 weights in one launch -------------
__global__ __launch_bounds__(256) void wcast_all_kernel(const float* __restrict__ W0,
                                                        const float* __restrict__ W1,
                                                        const float* __restrict__ W2,
                                                        const float* __restrict__ W3,
                                                        const float* __restrict__ W4,
                                                        const float* __restrict__ W5,
                                                        u16* __restrict__ wqt,
                                                        u16* __restrict__ wpt) {
    int y = blockIdx.y;
    int gid = blockIdx.x * 256 + threadIdx.x;
    const float* W; u16* dst; int K;
    if (y < 3) { W = (y == 0) ? W0 : (y == 1) ? W1 : W2; dst = wqt + y * 589824; K = 768;
                 if (gid >= 589824) return; }
    else       { W = (y == 3) ? W3 : (y == 4) ? W4 : W5; dst = wpt + (y - 3) * 196608; K = 256;
                 if (gid >= 196608) return; }
    int n = gid / K, k = gid - n * K;
    dst[gid] = f2b(W[(size_t)k * 768 + n]);
}

// ---------------- gate: idx = argmax(x @ Wg) ----------------
__global__ __launch_bounds__(256) void gate_kernel(const float* __restrict__ x,
                                                   const float* __restrict__ Wg,
                                                   int* __restrict__ idx,
                                                   float* __restrict__ out) {
    int t = blockIdx.x * 4 + (threadIdx.x >> 6);
    int lane = threadIdx.x & 63;
    const float* xr = x + (size_t)t * 768;
    float z0 = 0.f, z1 = 0.f, z2 = 0.f;
    for (int c = lane; c < 768; c += 64) {
        float xv = xr[c];
        z0 = fmaf(xv, Wg[c * 3 + 0], z0);
        z1 = fmaf(xv, Wg[c * 3 + 1], z1);
        z2 = fmaf(xv, Wg[c * 3 + 2], z2);
    }
    for (int o = 32; o; o >>= 1) {
        z0 += __shfl_xor(z0, o);
        z1 += __shfl_xor(z1, o);
        z2 += __shfl_xor(z2, o);
    }
    if (lane == 0) {
        int k = 0; float b = z0;
        if (z1 > b) { b = z1; k = 1; }
        if (z2 > b) { b = z2; k = 2; }
        idx[t] = k;
        out[12582912 + t] = (float)k;   // idx output
    }
}

// ---------------- QKV GEMM: xb[8192][768] @ Wqkv_t -> Q/K/V scatter ----------------
__global__ __launch_bounds__(256) void qkv_gemm_kernel(const u16* __restrict__ A,
                                                       const u16* __restrict__ Bt_all,
                                                       u16* __restrict__ Qo,
                                                       u16* __restrict__ Ko,
                                                       u16* __restrict__ Vt) {
    __shared__ u16 As[128 * 72];
    __shared__ u16 Bs[128 * 72];
    const int tid = threadIdx.x;
    const int lane = tid & 63, w = tid >> 6, wm = w >> 1, wn = w & 1;
    const int g = lane >> 4, c15 = lane & 15;
    const int branch = blockIdx.z;
    const int m0 = blockIdx.y * 128, n0 = blockIdx.x * 128;
    const u16* Bt = Bt_all + (size_t)branch * 589824;
    const int Kdim = 768, lda = 768, ldb = 768;

    f32x4 z4 = {0.f, 0.f, 0.f, 0.f};
    f32x4 acc[4][4];
    for (int mi = 0; mi < 4; mi++)
        for (int ni = 0; ni < 4; ni++) acc[mi][ni] = z4;

    for (int k0 = 0; k0 < Kdim; k0 += 64) {
        __syncthreads();
        for (int cidx = 0; cidx < 4; cidx++) {
            int i = cidx * 256 + tid;
            int row = i >> 3, cb = i & 7;
            *(s16x8*)&As[row * 72 + cb * 8] =
                *(const s16x8*)(A + (size_t)(m0 + row) * lda + k0 + cb * 8);
            *(s16x8*)&Bs[row * 72 + cb * 8] =
                *(const s16x8*)(Bt + (size_t)(n0 + row) * ldb + k0 + cb * 8);
        }
        __syncthreads();
        for (int kk = 0; kk < 2; kk++) {
            s16x8 af[4], bf[4];
            for (int i = 0; i < 4; i++) {
                af[i] = *(const s16x8*)&As[(wm * 64 + i * 16 + c15) * 72 + kk * 32 + g * 8];
                bf[i] = *(const s16x8*)&Bs[(wn * 64 + i * 16 + c15) * 72 + kk * 32 + g * 8];
            }
            for (int mi = 0; mi < 4; mi++)
                for (int ni = 0; ni < 4; ni++)
                    acc[mi][ni] = __builtin_amdgcn_mfma_f32_16x16x32_bf16(
                        af[mi], bf[ni], acc[mi][ni], 0, 0, 0);
        }
    }

    for (int mi = 0; mi < 4; mi++) {
        int r = m0 + wm * 64 + mi * 16 + g * 4;
        int batch = r >> 11, nbase = r & 2047;
        for (int ni = 0; ni < 4; ni++) {
            int cN = n0 + wn * 64 + ni * 16 + c15;
            int p = cN >> 8, h = (cN >> 6) & 3, d = cN & 63;
            size_t hb = (size_t)((branch * 4 + batch) * 4 + h) * 131072;
            f32x4 v = acc[mi][ni];
            if (p == 2) {
                s16x4 pk;
                for (int rg = 0; rg < 4; rg++) pk[rg] = (short)f2b(v[rg]);
                int pos = nbase & 31;
                int slot = ((pos & 15) >> 2) * 8 + ((pos >> 4) << 2);
                *(s16x4*)(Vt + hb + (size_t)d * 2048 + (nbase & ~31) + slot) = pk;
            } else if (p == 0) {
                for (int rg = 0; rg < 4; rg++)
                    Qo[hb + (size_t)(nbase + rg) * 64 + d] = f2b(v[rg] * QSCALE);
            } else {
                for (int rg = 0; rg < 4; rg++)
                    Ko[hb + (size_t)(nbase + rg) * 64 + d] = f2b(v[rg]);
            }
        }
    }
}

// ---------------- flash attention: LDS-staged K/V, fixed-max streaming softmax ----------------
// Block = 4 waves = 4 q-tiles of one XCD-pinned instance; 64-kpos K/V tiles staged to LDS
// via global_load_lds (double-buffered), XOR-swizzled chunks (swz on source + read).
#define ATTN_STEP(KF, VF) do {                                                              \
    _Pragma("unroll")                                                                       \
    for (int s = 0; s < 2; s++) {                                                           \
        f32x4 sa0 = __builtin_amdgcn_mfma_f32_16x16x32_bf16(KF[0][0], qf[s][0], z4, 0, 0, 0); \
        sa0 = __builtin_amdgcn_mfma_f32_16x16x32_bf16(KF[0][1], qf[s][1], sa0, 0, 0, 0);    \
        f32x4 sa1 = __builtin_amdgcn_mfma_f32_16x16x32_bf16(KF[1][0], qf[s][0], z4, 0, 0, 0); \
        sa1 = __builtin_amdgcn_mfma_f32_16x16x32_bf16(KF[1][1], qf[s][1], sa1, 0, 0, 0);    \
        float q0 = fexp2(sa0[0]), q1 = fexp2(sa0[1]);                                       \
        float q2 = fexp2(sa0[2]), q3 = fexp2(sa0[3]);                                       \
        float q4 = fexp2(sa1[0]), q5 = fexp2(sa1[1]);                                       \
        float q6 = fexp2(sa1[2]), q7 = fexp2(sa1[3]);                                       \
        lsp[s] += ((q0 + q1) + (q2 + q3)) + ((q4 + q5) + (q6 + q7));                        \
        u32x4 pw;                                                                           \
        pw[0] = cvtpk(q0, q1); pw[1] = cvtpk(q2, q3);                                       \
        pw[2] = cvtpk(q4, q5); pw[3] = cvtpk(q6, q7);                                       \
        union { u32x4 w; s16x8 h; } pu; pu.w = pw;                                          \
        s16x8 pb = pu.h;                                                                    \
        _Pragma("unroll")                                                                   \
        for (int dt = 0; dt < 4; dt++)                                                      \
            oac[s][dt] = __builtin_amdgcn_mfma_f32_16x16x32_bf16(VF[dt], pb, oac[s][dt], 0, 0, 0); \
    }                                                                                       \
} while (0)

// stage 64-kpos tile T into buffer B (4 x 1KB DMA per wave; 16 total per block)
#define STAGE(B, T) do {                                                  \
    const unsigned char* _ks = Ksrc + (size_t)(T) * 8192;                 \
    const unsigned char* _vs = Vsrc + (size_t)(T) * 128;                  \
    unsigned char* _kd = &lds[(B) * 16384 + w * 2048];                    \
    unsigned char* _vd = &lds[(B) * 16384 + 8192 + w * 2048];             \
    GLL(_ks, _kd); GLL(_ks + 1024, _kd + 1024);                           \
    GLL(_vs, _vd); GLL(_vs + 32768, _vd + 1024);                          \
} while (0)

#define TILE_STEP(B) do {                                                               \
    const unsigned char* _KL = &lds[(B) * 16384];                                       \
    const unsigned char* _VL = &lds[(B) * 16384 + 8192];                                \
    s16x8 kf[2][2], vf[4];                                                              \
    _Pragma("unroll")                                                                   \
    for (int t = 0; t < 2; t++)                                                         \
        _Pragma("unroll")                                                               \
        for (int h = 0; h < 2; h++)                                                     \
            kf[t][h] = *(const s16x8*)(_KL + (t * 16 + c) * 128 + (((h * 4 + g) ^ cx) * 16)); \
    _Pragma("unroll")                                                                   \
    for (int dt = 0; dt < 4; dt++)                                                      \
        vf[dt] = *(const s16x8*)(_VL + (dt * 16 + c) * 128 + ((g ^ cx) * 16));          \
    ATTN_STEP(kf, vf);                                                                  \
    _Pragma("unroll")                                                                   \
    for (int t = 0; t < 2; t++)                                                         \
        _Pragma("unroll")                                                               \
        for (int h = 0; h < 2; h++)                                                     \
            kf[t][h] = *(const s16x8*)(_KL + ((t + 2) * 16 + c) * 128 + (((h * 4 + g) ^ cx) * 16)); \
    _Pragma("unroll")                                                                   \
    for (int dt = 0; dt < 4; dt++)                                                      \
        vf[dt] = *(const s16x8*)(_VL + (dt * 16 + c) * 128 + (((4 + g) ^ cx) * 16));    \
    ATTN_STEP(kf, vf);                                                                  \
} while (0)

__global__ __launch_bounds__(256, 4) void attn_kernel(const u16* __restrict__ Qg,
                                                      const u16* __restrict__ Kg,
                                                      const u16* __restrict__ Vg,
                                                      u16* __restrict__ Og) {
    __shared__ unsigned char lds[32768];
    const int tid = threadIdx.x;
    const int w = tid >> 6, lane = tid & 63;
    const int b = blockIdx.x;
    const int j = b >> 3;
    const int inst = (b & 7) * 6 + (j % 6);   // XCD-pinned instance
    const int qt = (j / 6) * 4 + w;           // q-tile of 32 rows
    const int g = lane >> 4, c = lane & 15;
    const int cx = c & 7;
    const u16* Qh = Qg + (size_t)inst * 131072;

    f32x4 z4 = {0.f, 0.f, 0.f, 0.f};
    s16x8 qf[2][2];
    #pragma unroll
    for (int s = 0; s < 2; s++)
        #pragma unroll
        for (int kk = 0; kk < 2; kk++)
            qf[s][kk] = *(const s16x8*)(Qh + (size_t)(qt * 32 + s * 16 + c) * 64 + kk * 32 + g * 8);

    f32x4 oac[2][4];
    #pragma unroll
    for (int s = 0; s < 2; s++)
        #pragma unroll
        for (int dt = 0; dt < 4; dt++) oac[s][dt] = z4;
    float lsp[2] = {0.f, 0.f};

    // staging source addresses (per-lane, chunk-swizzled: j ^= row&7 within each 128B row)
    const int swz = (((lane & 7) ^ ((lane >> 3) & 7)) << 4);
    const unsigned char* Ksrc = (const unsigned char*)(Kg + (size_t)inst * 131072)
                                + w * 2048 + ((lane >> 3) << 7) + swz;
    const unsigned char* Vsrc = (const unsigned char*)(Vg + (size_t)inst * 131072)
                                + (size_t)w * 65536 + ((lane >> 3) << 12) + swz;

    STAGE(0, 0);
    __syncthreads();
    for (int t2 = 0; t2 < 32; t2++) {
        int cur = t2 & 1;
        if (t2 + 1 < 32) STAGE(cur ^ 1, t2 + 1);
        TILE_STEP(cur);
        __syncthreads();
    }

    int branch = inst >> 4, batch = (inst >> 2) & 3, h = inst & 3;
    #pragma unroll
    for (int s = 0; s < 2; s++) {
        float ls = lsp[s];
        ls += __shfl_xor(ls, 16);
        ls += __shfl_xor(ls, 32);
        float inv = 1.0f / ls;
        int n = qt * 32 + s * 16 + c;
        u16* dst = Og + ((size_t)(branch * 4 + batch) * 2048 + n) * 256 + h * 64;
        #pragma unroll
        for (int dt = 0; dt < 4; dt++) {
            s16x4 ob;
            for (int rg = 0; rg < 4; rg++) ob[rg] = (short)f2b(oac[s][dt][rg] * inv);
            *(s16x4*)(dst + dt * 16 + g * 4) = ob;
        }
    }
}

// ---------------- proj GEMM: O_b[8192][256] @ Wp_t + bp, select by idx, dual f32 write ----------------
__global__ __launch_bounds__(256) void proj_gemm_kernel(const u16* __restrict__ Oall,
                                                        const u16* __restrict__ Wpt_all,
                                                        const int* __restrict__ idx,
                                                        const float* __restrict__ bp1,
                                                        const float* __restrict__ bp2,
                                                        const float* __restrict__ bp3,
                                                        float* __restrict__ out) {
    __shared__ u16 As[128 * 72];
    __shared__ u16 Bs[128 * 72];
    const int tid = threadIdx.x;
    const int lane = tid & 63, w = tid >> 6, wm = w >> 1, wn = w & 1;
    const int g = lane >> 4, c15 = lane & 15;
    const int branch = blockIdx.z;
    const int m0 = blockIdx.y * 128, n0 = blockIdx.x * 128;
    const u16* A = Oall + (size_t)branch * 8192 * 256;
    const u16* Bt = Wpt_all + (size_t)branch * 196608;
    const float* bp = (branch == 0) ? bp1 : ((branch == 1) ? bp2 : bp3);
    const int Kdim = 256, lda = 256, ldb = 256;

    f32x4 z4 = {0.f, 0.f, 0.f, 0.f};
    f32x4 acc[4][4];
    for (int mi = 0; mi < 4; mi++)
        for (int ni = 0; ni < 4; ni++) acc[mi][ni] = z4;

    for (int k0 = 0; k0 < Kdim; k0 += 64) {
        __syncthreads();
        for (int cidx = 0; cidx < 4; cidx++) {
            int i = cidx * 256 + tid;
            int row = i >> 3, cb = i & 7;
            *(s16x8*)&As[row * 72 + cb * 8] =
                *(const s16x8*)(A + (size_t)(m0 + row) * lda + k0 + cb * 8);
            *(s16x8*)&Bs[row * 72 + cb * 8] =
                *(const s16x8*)(Bt + (size_t)(n0 + row) * ldb + k0 + cb * 8);
        }
        __syncthreads();
        for (int kk = 0; kk < 2; kk++) {
            s16x8 af[4], bf[4];
            for (int i = 0; i < 4; i++) {
                af[i] = *(const s16x8*)&As[(wm * 64 + i * 16 + c15) * 72 + kk * 32 + g * 8];
                bf[i] = *(const s16x8*)&Bs[(wn * 64 + i * 16 + c15) * 72 + kk * 32 + g * 8];
            }
            for (int mi = 0; mi < 4; mi++)
                for (int ni = 0; ni < 4; ni++)
                    acc[mi][ni] = __builtin_amdgcn_mfma_f32_16x16x32_bf16(
                        af[mi], bf[ni], acc[mi][ni], 0, 0, 0);
        }
    }

    for (int mi = 0; mi < 4; mi++) {
        int r = m0 + wm * 64 + mi * 16 + g * 4;
        for (int ni = 0; ni < 4; ni++) {
            int cN = n0 + wn * 64 + ni * 16 + c15;
            float bj = bp[cN];
            f32x4 v = acc[mi][ni];
            for (int rg = 0; rg < 4; rg++) {
                int t = r + rg;
                if (idx[t] == branch) {
                    float wv = v[rg] + bj;
                    out[(size_t)t * 768 + cN] = wv;                 // xo
                    out[6291456u + (size_t)t * 768 + cN] = wv;      // xd
                }
            }
        }
    }
}

extern "C" void kernel_launch(void* const* d_in, const int* in_sizes, int n_in,
                              void* d_out, int out_size, void* d_ws, size_t ws_size,
                              hipStream_t stream) {
    const float* x   = (const float*)d_in[0];
    const float* Wq1 = (const float*)d_in[1];
    const float* Wq2 = (const float*)d_in[2];
    const float* Wq3 = (const float*)d_in[3];
    const float* Wp1 = (const float*)d_in[4];
    const float* bp1 = (const float*)d_in[5];
    const float* Wp2 = (const float*)d_in[6];
    const float* bp2 = (const float*)d_in[7];
    const float* Wp3 = (const float*)d_in[8];
    const float* bp3 = (const float*)d_in[9];
    const float* Wg  = (const float*)d_in[10];
    float* out = (float*)d_out;

    char* ws = (char*)d_ws;
    u16* xb  = (u16*)(ws + 0);          // 12582912 B
    u16* wqt = (u16*)(ws + 12582912);   // 3538944 B
    u16* wpt = (u16*)(ws + 16121856);   // 1179648 B
    u16* Qb  = (u16*)(ws + 17301504);   // 12582912 B (48 x [2048][64], pre-scaled)
    u16* Kb  = (u16*)(ws + 29884416);   // 12582912 B
    u16* Vtb = (u16*)(ws + 42467328);   // 12582912 B (48 x [64][2048], slot-remapped)
    u16* Ob  = (u16*)(ws + 55050240);   // 12582912 B (3 x [8192][256])
    int* idx = (int*)(ws + 67633152);   // 32768 B

    cast_x_kernel<<<3072, 256, 0, stream>>>(x, xb);
    wcast_all_kernel<<<dim3(2304, 6), 256, 0, stream>>>(Wq1, Wq2, Wq3, Wp1, Wp2, Wp3, wqt, wpt);
    gate_kernel<<<2048, 256, 0, stream>>>(x, Wg, idx, out);
    qkv_gemm_kernel<<<dim3(6, 64, 3), 256, 0, stream>>>(xb, wqt, Qb, Kb, Vtb);
    attn_kernel<<<768, 256, 0, stream>>>(Qb, Kb, Vtb, Ob);
    proj_gemm_kernel<<<dim3(6, 64, 3), 256, 0, stream>>>(Ob, wpt, idx, bp1, bp2, bp3, out);
}

// Round 8
// 165.361 us; speedup vs baseline: 2.3618x; 1.0953x over previous
//
#include <hip/hip_runtime.h>

typedef short s16x4 __attribute__((ext_vector_type(4)));
typedef short s16x8 __attribute__((ext_vector_type(8)));
typedef float f32x4 __attribute__((ext_vector_type(4)));
typedef unsigned u32x4 __attribute__((ext_vector_type(4)));
typedef unsigned short u16;

__device__ __forceinline__ u16 f2b(float f) {
    union { float f; unsigned u; } v; v.f = f;
    unsigned r = v.u + 0x7FFFu + ((v.u >> 16) & 1u);
    return (u16)(r >> 16);
}

__device__ __forceinline__ float fexp2(float x) {
    float r; asm("v_exp_f32 %0, %1" : "=v"(r) : "v"(x)); return r;
}

__device__ __forceinline__ unsigned cvtpk(float lo, float hi) {
    unsigned r; asm("v_cvt_pk_bf16_f32 %0, %1, %2" : "=v"(r) : "v"(lo), "v"(hi)); return r;
}

__device__ __forceinline__ void GLL(const void* g, void* l) {
    __builtin_amdgcn_global_load_lds(
        (const __attribute__((address_space(1))) unsigned int*)g,
        (__attribute__((address_space(3))) unsigned int*)l, 16, 0, 0);
}

// Q pre-scale: hd^-0.5 * log2(e) so attention uses v_exp_f32 (2^x) directly
#define QSCALE 0.1803368801111244f

// ---------------- fused cast x->bf16 + gate argmax ----------------
__global__ __launch_bounds__(256) void castgate_kernel(const float* __restrict__ x,
                                                       const float* __restrict__ Wg,
                                                       u16* __restrict__ xb,
                                                       int* __restrict__ idx,
                                                       float* __restrict__ out) {
    int t = blockIdx.x * 4 + (threadIdx.x >> 6);
    int lane = threadIdx.x & 63;
    const float* xr = x + (size_t)t * 768;
    u16* xw = xb + (size_t)t * 768;
    float z0 = 0.f, z1 = 0.f, z2 = 0.f;
    #pragma unroll
    for (int s = 0; s < 3; s++) {
        int base = s * 256 + lane * 4;
        f32x4 v = *(const f32x4*)(xr + base);
        s16x4 o;
        #pragma unroll
        for (int j = 0; j < 4; j++) {
            o[j] = (short)f2b(v[j]);
            z0 = fmaf(v[j], Wg[(base + j) * 3 + 0], z0);
            z1 = fmaf(v[j], Wg[(base + j) * 3 + 1], z1);
            z2 = fmaf(v[j], Wg[(base + j) * 3 + 2], z2);
        }
        *(s16x4*)(xw + base) = o;
    }
    for (int o = 32; o; o >>= 1) {
        z0 += __shfl_xor(z0, o);
        z1 += __shfl_xor(z1, o);
        z2 += __shfl_xor(z2, o);
    }
    if (lane == 0) {
        int k = 0; float b = z0;
        if (z1 > b) { b = z1; k = 1; }
        if (z2 > b) { b = z2; k = 2; }
        idx[t] = k;
        out[12582912 + t] = (float)k;   // idx output
    }
}

// ------------- transpose + cast all 6 weights, LDS 32x32 tiles -------------
__global__ __launch_bounds__(256) void wcast_all_kernel(const float* __restrict__ W0,
                                                        const float* __restrict__ W1,
                                                        const float* __restrict__ W2,
                                                        const float* __restrict__ W3,
                                                        const float* __restrict__ W4,
                                                        const float* __restrict__ W5,
                                                        u16* __restrict__ wqt,
                                                        u16* __restrict__ wpt) {
    __shared__ u16 tile[32][34];
    int y = blockIdx.y;
    const float* W; u16* dst; int K;
    if (y < 3) { W = (y == 0) ? W0 : (y == 1) ? W1 : W2; dst = wqt + y * 589824; K = 768; }
    else       { W = (y == 3) ? W3 : (y == 4) ? W4 : W5; dst = wpt + (y - 3) * 196608; K = 256; }
    int ktiles = K >> 5;
    int bt = blockIdx.x;
    if (bt >= ktiles * 24) return;
    int kt = bt % ktiles, nt = bt / ktiles;
    int tx = threadIdx.x & 31, ty = threadIdx.x >> 5;
    #pragma unroll
    for (int i = 0; i < 4; i++) {
        int k = kt * 32 + ty + i * 8;
        tile[ty + i * 8][tx] = f2b(W[(size_t)k * 768 + nt * 32 + tx]);
    }
    __syncthreads();
    #pragma unroll
    for (int i = 0; i < 4; i++) {
        int n = nt * 32 + ty + i * 8;
        dst[(size_t)n * K + kt * 32 + tx] = tile[tx][ty + i * 8];
    }
}

// ---------------- QKV GEMM (R6-proven body): xb @ Wqkv_t -> Q/K/V scatter ----------------
__global__ __launch_bounds__(256) void qkv_gemm_kernel(const u16* __restrict__ A,
                                                       const u16* __restrict__ Bt_all,
                                                       u16* __restrict__ Qo,
                                                       u16* __restrict__ Ko,
                                                       u16* __restrict__ Vt) {
    __shared__ u16 As[128 * 72];
    __shared__ u16 Bs[128 * 72];
    const int tid = threadIdx.x;
    const int lane = tid & 63, w = tid >> 6, wm = w >> 1, wn = w & 1;
    const int g = lane >> 4, c15 = lane & 15;
    const int branch = blockIdx.z;
    const int m0 = blockIdx.y * 128, n0 = blockIdx.x * 128;
    const u16* Bt = Bt_all + (size_t)branch * 589824;
    const int Kdim = 768, lda = 768, ldb = 768;

    f32x4 z4 = {0.f, 0.f, 0.f, 0.f};
    f32x4 acc[4][4];
    for (int mi = 0; mi < 4; mi++)
        for (int ni = 0; ni < 4; ni++) acc[mi][ni] = z4;

    for (int k0 = 0; k0 < Kdim; k0 += 64) {
        __syncthreads();
        for (int cidx = 0; cidx < 4; cidx++) {
            int i = cidx * 256 + tid;
            int row = i >> 3, cb = i & 7;
            *(s16x8*)&As[row * 72 + cb * 8] =
                *(const s16x8*)(A + (size_t)(m0 + row) * lda + k0 + cb * 8);
            *(s16x8*)&Bs[row * 72 + cb * 8] =
                *(const s16x8*)(Bt + (size_t)(n0 + row) * ldb + k0 + cb * 8);
        }
        __syncthreads();
        for (int kk = 0; kk < 2; kk++) {
            s16x8 af[4], bf[4];
            for (int i = 0; i < 4; i++) {
                af[i] = *(const s16x8*)&As[(wm * 64 + i * 16 + c15) * 72 + kk * 32 + g * 8];
                bf[i] = *(const s16x8*)&Bs[(wn * 64 + i * 16 + c15) * 72 + kk * 32 + g * 8];
            }
            for (int mi = 0; mi < 4; mi++)
                for (int ni = 0; ni < 4; ni++)
                    acc[mi][ni] = __builtin_amdgcn_mfma_f32_16x16x32_bf16(
                        af[mi], bf[ni], acc[mi][ni], 0, 0, 0);
        }
    }

    for (int mi = 0; mi < 4; mi++) {
        int r = m0 + wm * 64 + mi * 16 + g * 4;
        int batch = r >> 11, nbase = r & 2047;
        for (int ni = 0; ni < 4; ni++) {
            int cN = n0 + wn * 64 + ni * 16 + c15;
            int p = cN >> 8, h = (cN >> 6) & 3, d = cN & 63;
            size_t hb = (size_t)((branch * 4 + batch) * 4 + h) * 131072;
            f32x4 v = acc[mi][ni];
            if (p == 2) {
                s16x4 pk;
                for (int rg = 0; rg < 4; rg++) pk[rg] = (short)f2b(v[rg]);
                int pos = nbase & 31;
                int slot = ((pos & 15) >> 2) * 8 + ((pos >> 4) << 2);
                *(s16x4*)(Vt + hb + (size_t)d * 2048 + (nbase & ~31) + slot) = pk;
            } else if (p == 0) {
                for (int rg = 0; rg < 4; rg++)
                    Qo[hb + (size_t)(nbase + rg) * 64 + d] = f2b(v[rg] * QSCALE);
            } else {
                for (int rg = 0; rg < 4; rg++)
                    Ko[hb + (size_t)(nbase + rg) * 64 + d] = f2b(v[rg]);
            }
        }
    }
}

// ---------------- flash attention: LDS-staged K/V, fixed-max streaming softmax ----------------
#define ATTN_STEP(KF, VF) do {                                                              \
    _Pragma("unroll")                                                                       \
    for (int s = 0; s < 2; s++) {                                                           \
        f32x4 sa0 = __builtin_amdgcn_mfma_f32_16x16x32_bf16(KF[0][0], qf[s][0], z4, 0, 0, 0); \
        sa0 = __builtin_amdgcn_mfma_f32_16x16x32_bf16(KF[0][1], qf[s][1], sa0, 0, 0, 0);    \
        f32x4 sa1 = __builtin_amdgcn_mfma_f32_16x16x32_bf16(KF[1][0], qf[s][0], z4, 0, 0, 0); \
        sa1 = __builtin_amdgcn_mfma_f32_16x16x32_bf16(KF[1][1], qf[s][1], sa1, 0, 0, 0);    \
        float q0 = fexp2(sa0[0]), q1 = fexp2(sa0[1]);                                       \
        float q2 = fexp2(sa0[2]), q3 = fexp2(sa0[3]);                                       \
        float q4 = fexp2(sa1[0]), q5 = fexp2(sa1[1]);                                       \
        float q6 = fexp2(sa1[2]), q7 = fexp2(sa1[3]);                                       \
        lsp[s] += ((q0 + q1) + (q2 + q3)) + ((q4 + q5) + (q6 + q7));                        \
        u32x4 pw;                                                                           \
        pw[0] = cvtpk(q0, q1); pw[1] = cvtpk(q2, q3);                                       \
        pw[2] = cvtpk(q4, q5); pw[3] = cvtpk(q6, q7);                                       \
        union { u32x4 w; s16x8 h; } pu; pu.w = pw;                                          \
        s16x8 pb = pu.h;                                                                    \
        _Pragma("unroll")                                                                   \
        for (int dt = 0; dt < 4; dt++)                                                      \
            oac[s][dt] = __builtin_amdgcn_mfma_f32_16x16x32_bf16(VF[dt], pb, oac[s][dt], 0, 0, 0); \
    }                                                                                       \
} while (0)

#define STAGE(B, T) do {                                                  \
    const unsigned char* _ks = Ksrc + (size_t)(T) * 8192;                 \
    const unsigned char* _vs = Vsrc + (size_t)(T) * 128;                  \
    unsigned char* _kd = &lds[(B) * 16384 + w * 2048];                    \
    unsigned char* _vd = &lds[(B) * 16384 + 8192 + w * 2048];             \
    GLL(_ks, _kd); GLL(_ks + 1024, _kd + 1024);                           \
    GLL(_vs, _vd); GLL(_vs + 32768, _vd + 1024);                          \
} while (0)

#define TILE_STEP(B) do {                                                               \
    const unsigned char* _KL = &lds[(B) * 16384];                                       \
    const unsigned char* _VL = &lds[(B) * 16384 + 8192];                                \
    s16x8 kf[2][2], vf[4];                                                              \
    _Pragma("unroll")                                                                   \
    for (int t = 0; t < 2; t++)                                                         \
        _Pragma("unroll")                                                               \
        for (int h = 0; h < 2; h++)                                                     \
            kf[t][h] = *(const s16x8*)(_KL + (t * 16 + c) * 128 + (((h * 4 + g) ^ cx) * 16)); \
    _Pragma("unroll")                                                                   \
    for (int dt = 0; dt < 4; dt++)                                                      \
        vf[dt] = *(const s16x8*)(_VL + (dt * 16 + c) * 128 + ((g ^ cx) * 16));          \
    ATTN_STEP(kf, vf);                                                                  \
    _Pragma("unroll")                                                                   \
    for (int t = 0; t < 2; t++)                                                         \
        _Pragma("unroll")                                                               \
        for (int h = 0; h < 2; h++)                                                     \
            kf[t][h] = *(const s16x8*)(_KL + ((t + 2) * 16 + c) * 128 + (((h * 4 + g) ^ cx) * 16)); \
    _Pragma("unroll")                                                                   \
    for (int dt = 0; dt < 4; dt++)                                                      \
        vf[dt] = *(const s16x8*)(_VL + (dt * 16 + c) * 128 + (((4 + g) ^ cx) * 16));    \
    ATTN_STEP(kf, vf);                                                                  \
} while (0)

__global__ __launch_bounds__(256, 4) void attn_kernel(const u16* __restrict__ Qg,
                                                      const u16* __restrict__ Kg,
                                                      const u16* __restrict__ Vg,
                                                      u16* __restrict__ Og) {
    __shared__ unsigned char lds[32768];
    const int tid = threadIdx.x;
    const int w = tid >> 6, lane = tid & 63;
    const int b = blockIdx.x;
    const int j = b >> 3;
    const int inst = (b & 7) * 6 + (j % 6);   // XCD-pinned instance
    const int qt = (j / 6) * 4 + w;           // q-tile of 32 rows
    const int g = lane >> 4, c = lane & 15;
    const int cx = c & 7;
    const u16* Qh = Qg + (size_t)inst * 131072;

    f32x4 z4 = {0.f, 0.f, 0.f, 0.f};
    s16x8 qf[2][2];
    #pragma unroll
    for (int s = 0; s < 2; s++)
        #pragma unroll
        for (int kk = 0; kk < 2; kk++)
            qf[s][kk] = *(const s16x8*)(Qh + (size_t)(qt * 32 + s * 16 + c) * 64 + kk * 32 + g * 8);

    f32x4 oac[2][4];
    #pragma unroll
    for (int s = 0; s < 2; s++)
        #pragma unroll
        for (int dt = 0; dt < 4; dt++) oac[s][dt] = z4;
    float lsp[2] = {0.f, 0.f};

    const int swz = (((lane & 7) ^ ((lane >> 3) & 7)) << 4);
    const unsigned char* Ksrc = (const unsigned char*)(Kg + (size_t)inst * 131072)
                                + w * 2048 + ((lane >> 3) << 7) + swz;
    const unsigned char* Vsrc = (const unsigned char*)(Vg + (size_t)inst * 131072)
                                + (size_t)w * 65536 + ((lane >> 3) << 12) + swz;

    STAGE(0, 0);
    __syncthreads();
    for (int t2 = 0; t2 < 32; t2++) {
        int cur = t2 & 1;
        if (t2 + 1 < 32) STAGE(cur ^ 1, t2 + 1);
        TILE_STEP(cur);
        __syncthreads();
    }

    int branch = inst >> 4, batch = (inst >> 2) & 3, h = inst & 3;
    #pragma unroll
    for (int s = 0; s < 2; s++) {
        float ls = lsp[s];
        ls += __shfl_xor(ls, 16);
        ls += __shfl_xor(ls, 32);
        float inv = 1.0f / ls;
        int n = qt * 32 + s * 16 + c;
        u16* dst = Og + ((size_t)(branch * 4 + batch) * 2048 + n) * 256 + h * 64;
        #pragma unroll
        for (int dt = 0; dt < 4; dt++) {
            s16x4 ob;
            for (int rg = 0; rg < 4; rg++) ob[rg] = (short)f2b(oac[s][dt][rg] * inv);
            *(s16x4*)(dst + dt * 16 + g * 4) = ob;
        }
    }
}

// ---------------- proj GEMM (R6-proven body): O_b @ Wp_t + bp, select, dual f32 write ----------------
__global__ __launch_bounds__(256) void proj_gemm_kernel(const u16* __restrict__ Oall,
                                                        const u16* __restrict__ Wpt_all,
                                                        const int* __restrict__ idx,
                                                        const float* __restrict__ bp1,
                                                        const float* __restrict__ bp2,
                                                        const float* __restrict__ bp3,
                                                        float* __restrict__ out) {
    __shared__ u16 As[128 * 72];
    __shared__ u16 Bs[128 * 72];
    const int tid = threadIdx.x;
    const int lane = tid & 63, w = tid >> 6, wm = w >> 1, wn = w & 1;
    const int g = lane >> 4, c15 = lane & 15;
    const int branch = blockIdx.z;
    const int m0 = blockIdx.y * 128, n0 = blockIdx.x * 128;
    const u16* A = Oall + (size_t)branch * 8192 * 256;
    const u16* Bt = Wpt_all + (size_t)branch * 196608;
    const float* bp = (branch == 0) ? bp1 : ((branch == 1) ? bp2 : bp3);
    const int Kdim = 256, lda = 256, ldb = 256;

    f32x4 z4 = {0.f, 0.f, 0.f, 0.f};
    f32x4 acc[4][4];
    for (int mi = 0; mi < 4; mi++)
        for (int ni = 0; ni < 4; ni++) acc[mi][ni] = z4;

    for (int k0 = 0; k0 < Kdim; k0 += 64) {
        __syncthreads();
        for (int cidx = 0; cidx < 4; cidx++) {
            int i = cidx * 256 + tid;
            int row = i >> 3, cb = i & 7;
            *(s16x8*)&As[row * 72 + cb * 8] =
                *(const s16x8*)(A + (size_t)(m0 + row) * lda + k0 + cb * 8);
            *(s16x8*)&Bs[row * 72 + cb * 8] =
                *(const s16x8*)(Bt + (size_t)(n0 + row) * ldb + k0 + cb * 8);
        }
        __syncthreads();
        for (int kk = 0; kk < 2; kk++) {
            s16x8 af[4], bf[4];
            for (int i = 0; i < 4; i++) {
                af[i] = *(const s16x8*)&As[(wm * 64 + i * 16 + c15) * 72 + kk * 32 + g * 8];
                bf[i] = *(const s16x8*)&Bs[(wn * 64 + i * 16 + c15) * 72 + kk * 32 + g * 8];
            }
            for (int mi = 0; mi < 4; mi++)
                for (int ni = 0; ni < 4; ni++)
                    acc[mi][ni] = __builtin_amdgcn_mfma_f32_16x16x32_bf16(
                        af[mi], bf[ni], acc[mi][ni], 0, 0, 0);
        }
    }

    for (int mi = 0; mi < 4; mi++) {
        int r = m0 + wm * 64 + mi * 16 + g * 4;
        for (int ni = 0; ni < 4; ni++) {
            int cN = n0 + wn * 64 + ni * 16 + c15;
            float bj = bp[cN];
            f32x4 v = acc[mi][ni];
            for (int rg = 0; rg < 4; rg++) {
                int t = r + rg;
                if (idx[t] == branch) {
                    float wv = v[rg] + bj;
                    out[(size_t)t * 768 + cN] = wv;                 // xo
                    out[6291456u + (size_t)t * 768 + cN] = wv;      // xd
                }
            }
        }
    }
}

extern "C" void kernel_launch(void* const* d_in, const int* in_sizes, int n_in,
                              void* d_out, int out_size, void* d_ws, size_t ws_size,
                              hipStream_t stream) {
    const float* x   = (const float*)d_in[0];
    const float* Wq1 = (const float*)d_in[1];
    const float* Wq2 = (const float*)d_in[2];
    const float* Wq3 = (const float*)d_in[3];
    const float* Wp1 = (const float*)d_in[4];
    const float* bp1 = (const float*)d_in[5];
    const float* Wp2 = (const float*)d_in[6];
    const float* bp2 = (const float*)d_in[7];
    const float* Wp3 = (const float*)d_in[8];
    const float* bp3 = (const float*)d_in[9];
    const float* Wg  = (const float*)d_in[10];
    float* out = (float*)d_out;

    char* ws = (char*)d_ws;
    u16* xb  = (u16*)(ws + 0);          // 12582912 B
    u16* wqt = (u16*)(ws + 12582912);   // 3538944 B
    u16* wpt = (u16*)(ws + 16121856);   // 1179648 B
    u16* Qb  = (u16*)(ws + 17301504);   // 12582912 B (48 x [2048][64], pre-scaled)
    u16* Kb  = (u16*)(ws + 29884416);   // 12582912 B
    u16* Vtb = (u16*)(ws + 42467328);   // 12582912 B (48 x [64][2048], slot-remapped)
    u16* Ob  = (u16*)(ws + 55050240);   // 12582912 B (3 x [8192][256])
    int* idx = (int*)(ws + 67633152);   // 32768 B

    castgate_kernel<<<2048, 256, 0, stream>>>(x, Wg, xb, idx, out);
    wcast_all_kernel<<<dim3(576, 6), 256, 0, stream>>>(Wq1, Wq2, Wq3, Wp1, Wp2, Wp3, wqt, wpt);
    qkv_gemm_kernel<<<dim3(6, 64, 3), 256, 0, stream>>>(xb, wqt, Qb, Kb, Vtb);
    attn_kernel<<<768, 256, 0, stream>>>(Qb, Kb, Vtb, Ob);
    proj_gemm_kernel<<<dim3(6, 64, 3), 256, 0, stream>>>(Ob, wpt, idx, bp1, bp2, bp3, out);
}

// Round 9
// 157.822 us; speedup vs baseline: 2.4746x; 1.0478x over previous
//
#include <hip/hip_runtime.h>

typedef short s16x4 __attribute__((ext_vector_type(4)));
typedef short s16x8 __attribute__((ext_vector_type(8)));
typedef float f32x4 __attribute__((ext_vector_type(4)));
typedef unsigned u32x4 __attribute__((ext_vector_type(4)));
typedef unsigned short u16;

__device__ __forceinline__ u16 f2b(float f) {
    union { float f; unsigned u; } v; v.f = f;
    unsigned r = v.u + 0x7FFFu + ((v.u >> 16) & 1u);
    return (u16)(r >> 16);
}

__device__ __forceinline__ float fexp2(float x) {
    float r; asm("v_exp_f32 %0, %1" : "=v"(r) : "v"(x)); return r;
}

__device__ __forceinline__ unsigned cvtpk(float lo, float hi) {
    unsigned r; asm("v_cvt_pk_bf16_f32 %0, %1, %2" : "=v"(r) : "v"(lo), "v"(hi)); return r;
}

__device__ __forceinline__ void GLL(const void* g, void* l) {
    __builtin_amdgcn_global_load_lds(
        (const __attribute__((address_space(1))) unsigned int*)g,
        (__attribute__((address_space(3))) unsigned int*)l, 16, 0, 0);
}

// explicit DMA drain: hipcc does NOT reliably emit vmcnt(0) for global_load_lds
// before s_barrier (R6 absmax drift + R7 NaN evidence)
__device__ __forceinline__ void vmwait0() {
    asm volatile("s_waitcnt vmcnt(0)" ::: "memory");
    __builtin_amdgcn_sched_barrier(0);
}

// Q pre-scale: hd^-0.5 * log2(e) so attention uses v_exp_f32 (2^x) directly
#define QSCALE 0.1803368801111244f

// ---------------- fused cast x->bf16 + gate argmax ----------------
__global__ __launch_bounds__(256) void castgate_kernel(const float* __restrict__ x,
                                                       const float* __restrict__ Wg,
                                                       u16* __restrict__ xb,
                                                       int* __restrict__ idx,
                                                       float* __restrict__ out) {
    int t = blockIdx.x * 4 + (threadIdx.x >> 6);
    int lane = threadIdx.x & 63;
    const float* xr = x + (size_t)t * 768;
    u16* xw = xb + (size_t)t * 768;
    float z0 = 0.f, z1 = 0.f, z2 = 0.f;
    #pragma unroll
    for (int s = 0; s < 3; s++) {
        int base = s * 256 + lane * 4;
        f32x4 v = *(const f32x4*)(xr + base);
        s16x4 o;
        #pragma unroll
        for (int j = 0; j < 4; j++) {
            o[j] = (short)f2b(v[j]);
            z0 = fmaf(v[j], Wg[(base + j) * 3 + 0], z0);
            z1 = fmaf(v[j], Wg[(base + j) * 3 + 1], z1);
            z2 = fmaf(v[j], Wg[(base + j) * 3 + 2], z2);
        }
        *(s16x4*)(xw + base) = o;
    }
    for (int o = 32; o; o >>= 1) {
        z0 += __shfl_xor(z0, o);
        z1 += __shfl_xor(z1, o);
        z2 += __shfl_xor(z2, o);
    }
    if (lane == 0) {
        int k = 0; float b = z0;
        if (z1 > b) { b = z1; k = 1; }
        if (z2 > b) { b = z2; k = 2; }
        idx[t] = k;
        out[12582912 + t] = (float)k;   // idx output
    }
}

// ------------- transpose + cast all 6 weights, LDS 32x32 tiles -------------
__global__ __launch_bounds__(256) void wcast_all_kernel(const float* __restrict__ W0,
                                                        const float* __restrict__ W1,
                                                        const float* __restrict__ W2,
                                                        const float* __restrict__ W3,
                                                        const float* __restrict__ W4,
                                                        const float* __restrict__ W5,
                                                        u16* __restrict__ wqt,
                                                        u16* __restrict__ wpt) {
    __shared__ u16 tile[32][34];
    int y = blockIdx.y;
    const float* W; u16* dst; int K;
    if (y < 3) { W = (y == 0) ? W0 : (y == 1) ? W1 : W2; dst = wqt + y * 589824; K = 768; }
    else       { W = (y == 3) ? W3 : (y == 4) ? W4 : W5; dst = wpt + (y - 3) * 196608; K = 256; }
    int ktiles = K >> 5;
    int bt = blockIdx.x;
    if (bt >= ktiles * 24) return;
    int kt = bt % ktiles, nt = bt / ktiles;
    int tx = threadIdx.x & 31, ty = threadIdx.x >> 5;
    #pragma unroll
    for (int i = 0; i < 4; i++) {
        int k = kt * 32 + ty + i * 8;
        tile[ty + i * 8][tx] = f2b(W[(size_t)k * 768 + nt * 32 + tx]);
    }
    __syncthreads();
    #pragma unroll
    for (int i = 0; i < 4; i++) {
        int n = nt * 32 + ty + i * 8;
        dst[(size_t)n * K + kt * 32 + tx] = tile[tx][ty + i * 8];
    }
}

// ---------------- QKV GEMM: GLL-staged, XOR chunk swizzle, explicit vmcnt drain ----------------
__global__ __launch_bounds__(256) void qkv_gemm_kernel(const u16* __restrict__ A,
                                                       const u16* __restrict__ Bt_all,
                                                       u16* __restrict__ Qo,
                                                       u16* __restrict__ Ko,
                                                       u16* __restrict__ Vt) {
    __shared__ u16 As[128 * 64];
    __shared__ u16 Bs[128 * 64];
    const int tid = threadIdx.x;
    const int lane = tid & 63, w = tid >> 6, wm = w >> 1, wn = w & 1;
    const int g = lane >> 4, c15 = lane & 15;
    const int cx = c15 & 7;
    const int branch = blockIdx.z;
    const int m0 = blockIdx.y * 128, n0 = blockIdx.x * 128;
    const u16* Bt = Bt_all + (size_t)branch * 589824;

    const int l8 = lane >> 3;
    const int ch = (lane & 7) ^ l8;      // swizzled source chunk: LDS[row][j] = G[row][j^(row&7)]
    const u16* Asrc = A + (size_t)(m0 + w * 32 + l8) * 768 + ch * 8;
    const u16* Bsrc = Bt + (size_t)(n0 + w * 32 + l8) * 768 + ch * 8;
    u16* AsW = As + w * 2048;
    u16* BsW = Bs + w * 2048;

    f32x4 z4 = {0.f, 0.f, 0.f, 0.f};
    f32x4 acc[4][4];
    for (int mi = 0; mi < 4; mi++)
        for (int ni = 0; ni < 4; ni++) acc[mi][ni] = z4;

    for (int k0 = 0; k0 < 768; k0 += 64) {
        __syncthreads();
        #pragma unroll
        for (int it = 0; it < 4; it++) {
            GLL(Asrc + (size_t)(it * 8) * 768 + k0, AsW + it * 512);
            GLL(Bsrc + (size_t)(it * 8) * 768 + k0, BsW + it * 512);
        }
        vmwait0();
        __syncthreads();
        #pragma unroll
        for (int kk = 0; kk < 2; kk++) {
            s16x8 af[4], bf[4];
            #pragma unroll
            for (int i = 0; i < 4; i++) {
                af[i] = *(const s16x8*)&As[(wm * 64 + i * 16 + c15) * 64 + (((kk * 4 + g) ^ cx) * 8)];
                bf[i] = *(const s16x8*)&Bs[(wn * 64 + i * 16 + c15) * 64 + (((kk * 4 + g) ^ cx) * 8)];
            }
            for (int mi = 0; mi < 4; mi++)
                for (int ni = 0; ni < 4; ni++)
                    acc[mi][ni] = __builtin_amdgcn_mfma_f32_16x16x32_bf16(
                        af[mi], bf[ni], acc[mi][ni], 0, 0, 0);
        }
    }

    for (int mi = 0; mi < 4; mi++) {
        int r = m0 + wm * 64 + mi * 16 + g * 4;
        int batch = r >> 11, nbase = r & 2047;
        for (int ni = 0; ni < 4; ni++) {
            int cN = n0 + wn * 64 + ni * 16 + c15;
            int p = cN >> 8, h = (cN >> 6) & 3, d = cN & 63;
            size_t hb = (size_t)((branch * 4 + batch) * 4 + h) * 131072;
            f32x4 v = acc[mi][ni];
            if (p == 2) {
                s16x4 pk;
                for (int rg = 0; rg < 4; rg++) pk[rg] = (short)f2b(v[rg]);
                int pos = nbase & 31;
                int slot = ((pos & 15) >> 2) * 8 + ((pos >> 4) << 2);
                *(s16x4*)(Vt + hb + (size_t)d * 2048 + (nbase & ~31) + slot) = pk;
            } else if (p == 0) {
                for (int rg = 0; rg < 4; rg++)
                    Qo[hb + (size_t)(nbase + rg) * 64 + d] = f2b(v[rg] * QSCALE);
            } else {
                for (int rg = 0; rg < 4; rg++)
                    Ko[hb + (size_t)(nbase + rg) * 64 + d] = f2b(v[rg]);
            }
        }
    }
}

// ---------------- flash attention: LDS-staged K/V, fixed-max streaming softmax ----------------
#define ATTN_STEP(KF, VF) do {                                                              \
    _Pragma("unroll")                                                                       \
    for (int s = 0; s < 2; s++) {                                                           \
        f32x4 sa0 = __builtin_amdgcn_mfma_f32_16x16x32_bf16(KF[0][0], qf[s][0], z4, 0, 0, 0); \
        sa0 = __builtin_amdgcn_mfma_f32_16x16x32_bf16(KF[0][1], qf[s][1], sa0, 0, 0, 0);    \
        f32x4 sa1 = __builtin_amdgcn_mfma_f32_16x16x32_bf16(KF[1][0], qf[s][0], z4, 0, 0, 0); \
        sa1 = __builtin_amdgcn_mfma_f32_16x16x32_bf16(KF[1][1], qf[s][1], sa1, 0, 0, 0);    \
        float q0 = fexp2(sa0[0]), q1 = fexp2(sa0[1]);                                       \
        float q2 = fexp2(sa0[2]), q3 = fexp2(sa0[3]);                                       \
        float q4 = fexp2(sa1[0]), q5 = fexp2(sa1[1]);                                       \
        float q6 = fexp2(sa1[2]), q7 = fexp2(sa1[3]);                                       \
        lsp[s] += ((q0 + q1) + (q2 + q3)) + ((q4 + q5) + (q6 + q7));                        \
        u32x4 pw;                                                                           \
        pw[0] = cvtpk(q0, q1); pw[1] = cvtpk(q2, q3);                                       \
        pw[2] = cvtpk(q4, q5); pw[3] = cvtpk(q6, q7);                                       \
        union { u32x4 w; s16x8 h; } pu; pu.w = pw;                                          \
        s16x8 pb = pu.h;                                                                    \
        _Pragma("unroll")                                                                   \
        for (int dt = 0; dt < 4; dt++)                                                      \
            oac[s][dt] = __builtin_amdgcn_mfma_f32_16x16x32_bf16(VF[dt], pb, oac[s][dt], 0, 0, 0); \
    }                                                                                       \
} while (0)

#define STAGE(B, T) do {                                                  \
    const unsigned char* _ks = Ksrc + (size_t)(T) * 8192;                 \
    const unsigned char* _vs = Vsrc + (size_t)(T) * 128;                  \
    unsigned char* _kd = &lds[(B) * 16384 + w * 2048];                    \
    unsigned char* _vd = &lds[(B) * 16384 + 8192 + w * 2048];             \
    GLL(_ks, _kd); GLL(_ks + 1024, _kd + 1024);                           \
    GLL(_vs, _vd); GLL(_vs + 32768, _vd + 1024);                          \
} while (0)

#define TILE_STEP(B) do {                                                               \
    const unsigned char* _KL = &lds[(B) * 16384];                                       \
    const unsigned char* _VL = &lds[(B) * 16384 + 8192];                                \
    s16x8 kf[2][2], vf[4];                                                              \
    _Pragma("unroll")                                                                   \
    for (int t = 0; t < 2; t++)                                                         \
        _Pragma("unroll")                                                               \
        for (int h = 0; h < 2; h++)                                                     \
            kf[t][h] = *(const s16x8*)(_KL + (t * 16 + c) * 128 + (((h * 4 + g) ^ cx) * 16)); \
    _Pragma("unroll")                                                                   \
    for (int dt = 0; dt < 4; dt++)                                                      \
        vf[dt] = *(const s16x8*)(_VL + (dt * 16 + c) * 128 + ((g ^ cx) * 16));          \
    ATTN_STEP(kf, vf);                                                                  \
    _Pragma("unroll")                                                                   \
    for (int t = 0; t < 2; t++)                                                         \
        _Pragma("unroll")                                                               \
        for (int h = 0; h < 2; h++)                                                     \
            kf[t][h] = *(const s16x8*)(_KL + ((t + 2) * 16 + c) * 128 + (((h * 4 + g) ^ cx) * 16)); \
    _Pragma("unroll")                                                                   \
    for (int dt = 0; dt < 4; dt++)                                                      \
        vf[dt] = *(const s16x8*)(_VL + (dt * 16 + c) * 128 + (((4 + g) ^ cx) * 16));    \
    ATTN_STEP(kf, vf);                                                                  \
} while (0)

__global__ __launch_bounds__(256, 4) void attn_kernel(const u16* __restrict__ Qg,
                                                      const u16* __restrict__ Kg,
                                                      const u16* __restrict__ Vg,
                                                      u16* __restrict__ Og) {
    __shared__ unsigned char lds[32768];
    const int tid = threadIdx.x;
    const int w = tid >> 6, lane = tid & 63;
    const int b = blockIdx.x;
    const int j = b >> 3;
    const int inst = (b & 7) * 6 + (j % 6);   // XCD-pinned instance
    const int qt = (j / 6) * 4 + w;           // q-tile of 32 rows
    const int g = lane >> 4, c = lane & 15;
    const int cx = c & 7;
    const u16* Qh = Qg + (size_t)inst * 131072;

    f32x4 z4 = {0.f, 0.f, 0.f, 0.f};
    s16x8 qf[2][2];
    #pragma unroll
    for (int s = 0; s < 2; s++)
        #pragma unroll
        for (int kk = 0; kk < 2; kk++)
            qf[s][kk] = *(const s16x8*)(Qh + (size_t)(qt * 32 + s * 16 + c) * 64 + kk * 32 + g * 8);

    f32x4 oac[2][4];
    #pragma unroll
    for (int s = 0; s < 2; s++)
        #pragma unroll
        for (int dt = 0; dt < 4; dt++) oac[s][dt] = z4;
    float lsp[2] = {0.f, 0.f};

    const int swz = (((lane & 7) ^ ((lane >> 3) & 7)) << 4);
    const unsigned char* Ksrc = (const unsigned char*)(Kg + (size_t)inst * 131072)
                                + w * 2048 + ((lane >> 3) << 7) + swz;
    const unsigned char* Vsrc = (const unsigned char*)(Vg + (size_t)inst * 131072)
                                + (size_t)w * 65536 + ((lane >> 3) << 12) + swz;

    STAGE(0, 0);
    vmwait0();
    __syncthreads();
    for (int t2 = 0; t2 < 32; t2++) {
        int cur = t2 & 1;
        if (t2 + 1 < 32) STAGE(cur ^ 1, t2 + 1);
        TILE_STEP(cur);
        vmwait0();
        __syncthreads();
    }

    int branch = inst >> 4, batch = (inst >> 2) & 3, h = inst & 3;
    #pragma unroll
    for (int s = 0; s < 2; s++) {
        float ls = lsp[s];
        ls += __shfl_xor(ls, 16);
        ls += __shfl_xor(ls, 32);
        float inv = 1.0f / ls;
        int n = qt * 32 + s * 16 + c;
        u16* dst = Og + ((size_t)(branch * 4 + batch) * 2048 + n) * 256 + h * 64;
        #pragma unroll
        for (int dt = 0; dt < 4; dt++) {
            s16x4 ob;
            for (int rg = 0; rg < 4; rg++) ob[rg] = (short)f2b(oac[s][dt][rg] * inv);
            *(s16x4*)(dst + dt * 16 + g * 4) = ob;
        }
    }
}

// ---------------- proj GEMM: GLL-staged, select by idx, dual f32 write ----------------
__global__ __launch_bounds__(256) void proj_gemm_kernel(const u16* __restrict__ Oall,
                                                        const u16* __restrict__ Wpt_all,
                                                        const int* __restrict__ idx,
                                                        const float* __restrict__ bp1,
                                                        const float* __restrict__ bp2,
                                                        const float* __restrict__ bp3,
                                                        float* __restrict__ out) {
    __shared__ u16 As[128 * 64];
    __shared__ u16 Bs[128 * 64];
    const int tid = threadIdx.x;
    const int lane = tid & 63, w = tid >> 6, wm = w >> 1, wn = w & 1;
    const int g = lane >> 4, c15 = lane & 15;
    const int cx = c15 & 7;
    const int branch = blockIdx.z;
    const int m0 = blockIdx.y * 128, n0 = blockIdx.x * 128;
    const u16* A = Oall + (size_t)branch * 8192 * 256;
    const u16* Bt = Wpt_all + (size_t)branch * 196608;
    const float* bp = (branch == 0) ? bp1 : ((branch == 1) ? bp2 : bp3);

    const int l8 = lane >> 3;
    const int ch = (lane & 7) ^ l8;
    const u16* Asrc = A + (size_t)(m0 + w * 32 + l8) * 256 + ch * 8;
    const u16* Bsrc = Bt + (size_t)(n0 + w * 32 + l8) * 256 + ch * 8;
    u16* AsW = As + w * 2048;
    u16* BsW = Bs + w * 2048;

    f32x4 z4 = {0.f, 0.f, 0.f, 0.f};
    f32x4 acc[4][4];
    for (int mi = 0; mi < 4; mi++)
        for (int ni = 0; ni < 4; ni++) acc[mi][ni] = z4;

    for (int k0 = 0; k0 < 256; k0 += 64) {
        __syncthreads();
        #pragma unroll
        for (int it = 0; it < 4; it++) {
            GLL(Asrc + (size_t)(it * 8) * 256 + k0, AsW + it * 512);
            GLL(Bsrc + (size_t)(it * 8) * 256 + k0, BsW + it * 512);
        }
        vmwait0();
        __syncthreads();
        #pragma unroll
        for (int kk = 0; kk < 2; kk++) {
            s16x8 af[4], bf[4];
            #pragma unroll
            for (int i = 0; i < 4; i++) {
                af[i] = *(const s16x8*)&As[(wm * 64 + i * 16 + c15) * 64 + (((kk * 4 + g) ^ cx) * 8)];
                bf[i] = *(const s16x8*)&Bs[(wn * 64 + i * 16 + c15) * 64 + (((kk * 4 + g) ^ cx) * 8)];
            }
            for (int mi = 0; mi < 4; mi++)
                for (int ni = 0; ni < 4; ni++)
                    acc[mi][ni] = __builtin_amdgcn_mfma_f32_16x16x32_bf16(
                        af[mi], bf[ni], acc[mi][ni], 0, 0, 0);
        }
    }

    for (int mi = 0; mi < 4; mi++) {
        int r = m0 + wm * 64 + mi * 16 + g * 4;
        for (int ni = 0; ni < 4; ni++) {
            int cN = n0 + wn * 64 + ni * 16 + c15;
            float bj = bp[cN];
            f32x4 v = acc[mi][ni];
            for (int rg = 0; rg < 4; rg++) {
                int t = r + rg;
                if (idx[t] == branch) {
                    float wv = v[rg] + bj;
                    out[(size_t)t * 768 + cN] = wv;                 // xo
                    out[6291456u + (size_t)t * 768 + cN] = wv;      // xd
                }
            }
        }
    }
}

extern "C" void kernel_launch(void* const* d_in, const int* in_sizes, int n_in,
                              void* d_out, int out_size, void* d_ws, size_t ws_size,
                              hipStream_t stream) {
    const float* x   = (const float*)d_in[0];
    const float* Wq1 = (const float*)d_in[1];
    const float* Wq2 = (const float*)d_in[2];
    const float* Wq3 = (const float*)d_in[3];
    const float* Wp1 = (const float*)d_in[4];
    const float* bp1 = (const float*)d_in[5];
    const float* Wp2 = (const float*)d_in[6];
    const float* bp2 = (const float*)d_in[7];
    const float* Wp3 = (const float*)d_in[8];
    const float* bp3 = (const float*)d_in[9];
    const float* Wg  = (const float*)d_in[10];
    float* out = (float*)d_out;

    char* ws = (char*)d_ws;
    u16* xb  = (u16*)(ws + 0);          // 12582912 B
    u16* wqt = (u16*)(ws + 12582912);   // 3538944 B
    u16* wpt = (u16*)(ws + 16121856);   // 1179648 B
    u16* Qb  = (u16*)(ws + 17301504);   // 12582912 B (48 x [2048][64], pre-scaled)
    u16* Kb  = (u16*)(ws + 29884416);   // 12582912 B
    u16* Vtb = (u16*)(ws + 42467328);   // 12582912 B (48 x [64][2048], slot-remapped)
    u16* Ob  = (u16*)(ws + 55050240);   // 12582912 B (3 x [8192][256])
    int* idx = (int*)(ws + 67633152);   // 32768 B

    castgate_kernel<<<2048, 256, 0, stream>>>(x, Wg, xb, idx, out);
    wcast_all_kernel<<<dim3(576, 6), 256, 0, stream>>>(Wq1, Wq2, Wq3, Wp1, Wp2, Wp3, wqt, wpt);
    qkv_gemm_kernel<<<dim3(6, 64, 3), 256, 0, stream>>>(xb, wqt, Qb, Kb, Vtb);
    attn_kernel<<<768, 256, 0, stream>>>(Qb, Kb, Vtb, Ob);
    proj_gemm_kernel<<<dim3(6, 64, 3), 256, 0, stream>>>(Ob, wpt, idx, bp1, bp2, bp3, out);
}

// Round 12
// 141.759 us; speedup vs baseline: 2.7550x; 1.1133x over previous
//
#include <hip/hip_runtime.h>

typedef short s16x4 __attribute__((ext_vector_type(4)));
typedef short s16x8 __attribute__((ext_vector_type(8)));
typedef float f32x4 __attribute__((ext_vector_type(4)));
typedef unsigned u32x4 __attribute__((ext_vector_type(4)));
typedef unsigned short u16;
typedef unsigned char u8;

__device__ __forceinline__ u16 f2b(float f) {
    union { float f; unsigned u; } v; v.f = f;
    unsigned r = v.u + 0x7FFFu + ((v.u >> 16) & 1u);
    return (u16)(r >> 16);
}

__device__ __forceinline__ float fexp2(float x) {
    float r; asm("v_exp_f32 %0, %1" : "=v"(r) : "v"(x)); return r;
}

__device__ __forceinline__ unsigned cvtpk(float lo, float hi) {
    unsigned r; asm("v_cvt_pk_bf16_f32 %0, %1, %2" : "=v"(r) : "v"(lo), "v"(hi)); return r;
}

__device__ __forceinline__ void GLL(const void* g, void* l) {
    __builtin_amdgcn_global_load_lds(
        (const __attribute__((address_space(1))) unsigned int*)g,
        (__attribute__((address_space(3))) unsigned int*)l, 16, 0, 0);
}

// explicit DMA drain before barriers that publish staged LDS (R6/R7 race evidence)
__device__ __forceinline__ void vmwait0() {
    asm volatile("s_waitcnt vmcnt(0)" ::: "memory");
    __builtin_amdgcn_sched_barrier(0);
}

// Q pre-scale: hd^-0.5 * log2(e) so attention uses v_exp_f32 (2^x) directly
#define QSCALE 0.1803368801111244f

// ---------------- fused cast x->bf16 + gate argmax ----------------
__global__ __launch_bounds__(256) void castgate_kernel(const float* __restrict__ x,
                                                       const float* __restrict__ Wg,
                                                       u16* __restrict__ xb,
                                                       u8* __restrict__ kArr,
                                                       float* __restrict__ out) {
    int t = blockIdx.x * 4 + (threadIdx.x >> 6);
    int lane = threadIdx.x & 63;
    const float* xr = x + (size_t)t * 768;
    u16* xw = xb + (size_t)t * 768;
    float z0 = 0.f, z1 = 0.f, z2 = 0.f;
    #pragma unroll
    for (int s = 0; s < 3; s++) {
        int base = s * 256 + lane * 4;
        f32x4 v = *(const f32x4*)(xr + base);
        s16x4 o;
        #pragma unroll
        for (int j = 0; j < 4; j++) {
            o[j] = (short)f2b(v[j]);
            z0 = fmaf(v[j], Wg[(base + j) * 3 + 0], z0);
            z1 = fmaf(v[j], Wg[(base + j) * 3 + 1], z1);
            z2 = fmaf(v[j], Wg[(base + j) * 3 + 2], z2);
        }
        *(s16x4*)(xw + base) = o;
    }
    for (int o = 32; o; o >>= 1) {
        z0 += __shfl_xor(z0, o);
        z1 += __shfl_xor(z1, o);
        z2 += __shfl_xor(z2, o);
    }
    if (lane == 0) {
        int k = 0; float b = z0;
        if (z1 > b) { b = z1; k = 1; }
        if (z2 > b) { b = z2; k = 2; }
        out[12582912 + t] = (float)k;   // idx output
        kArr[t] = (u8)k;
    }
}

// ---------------- deterministic ballot compaction: per-batch permutation ----------------
__global__ __launch_bounds__(64) void compact_kernel(const u8* __restrict__ kArr,
                                                     u16* __restrict__ perm,
                                                     int* __restrict__ cnt,
                                                     int* __restrict__ startA) {
    int batch = blockIdx.x;
    int lane = threadIdx.x;
    const u8* ka = kArr + batch * 2048;
    u16* pm = perm + batch * 2048;
    int off = 0;
    for (int br = 0; br < 3; br++) {
        int c = 0;
        for (int b0 = 0; b0 < 2048; b0 += 64) {
            bool p = (ka[b0 + lane] == (u8)br);
            unsigned long long m = __ballot(p);
            int rank = __popcll(m & ((1ull << lane) - 1ull));
            if (p) pm[off + c + rank] = (u16)(b0 + lane);
            c += __popcll(m);
        }
        if (lane == 0) { cnt[br * 4 + batch] = c; startA[br * 4 + batch] = off; }
        off += c;
    }
}

// ------------- transpose + cast all 6 weights, LDS 32x32 tiles -------------
__global__ __launch_bounds__(256) void wcast_all_kernel(const float* __restrict__ W0,
                                                        const float* __restrict__ W1,
                                                        const float* __restrict__ W2,
                                                        const float* __restrict__ W3,
                                                        const float* __restrict__ W4,
                                                        const float* __restrict__ W5,
                                                        u16* __restrict__ wqt,
                                                        u16* __restrict__ wpt) {
    __shared__ u16 tile[32][34];
    int y = blockIdx.y;
    const float* W; u16* dst; int K;
    if (y < 3) { W = (y == 0) ? W0 : (y == 1) ? W1 : W2; dst = wqt + y * 589824; K = 768; }
    else       { W = (y == 3) ? W3 : (y == 4) ? W4 : W5; dst = wpt + (y - 3) * 196608; K = 256; }
    int ktiles = K >> 5;
    int bt = blockIdx.x;
    if (bt >= ktiles * 24) return;
    int kt = bt % ktiles, nt = bt / ktiles;
    int tx = threadIdx.x & 31, ty = threadIdx.x >> 5;
    #pragma unroll
    for (int i = 0; i < 4; i++) {
        int k = kt * 32 + ty + i * 8;
        tile[ty + i * 8][tx] = f2b(W[(size_t)k * 768 + nt * 32 + tx]);
    }
    __syncthreads();
    #pragma unroll
    for (int i = 0; i < 4; i++) {
        int n = nt * 32 + ty + i * 8;
        dst[(size_t)n * K + kt * 32 + tx] = tile[tx][ty + i * 8];
    }
}

// ---------------- QKV GEMM: GLL-staged, XOR chunk swizzle, explicit vmcnt drain ----------------
__global__ __launch_bounds__(256) void qkv_gemm_kernel(const u16* __restrict__ A,
                                                       const u16* __restrict__ Bt_all,
                                                       u16* __restrict__ Qo,
                                                       u16* __restrict__ Ko,
                                                       u16* __restrict__ Vt) {
    __shared__ u16 As[128 * 64];
    __shared__ u16 Bs[128 * 64];
    const int tid = threadIdx.x;
    const int lane = tid & 63, w = tid >> 6, wm = w >> 1, wn = w & 1;
    const int g = lane >> 4, c15 = lane & 15;
    const int cx = c15 & 7;
    const int branch = blockIdx.z;
    const int m0 = blockIdx.y * 128, n0 = blockIdx.x * 128;
    const u16* Bt = Bt_all + (size_t)branch * 589824;

    const int l8 = lane >> 3;
    const int ch = (lane & 7) ^ l8;      // swizzled source chunk: LDS[row][j] = G[row][j^(row&7)]
    const u16* Asrc = A + (size_t)(m0 + w * 32 + l8) * 768 + ch * 8;
    const u16* Bsrc = Bt + (size_t)(n0 + w * 32 + l8) * 768 + ch * 8;
    u16* AsW = As + w * 2048;
    u16* BsW = Bs + w * 2048;

    f32x4 z4 = {0.f, 0.f, 0.f, 0.f};
    f32x4 acc[4][4];
    for (int mi = 0; mi < 4; mi++)
        for (int ni = 0; ni < 4; ni++) acc[mi][ni] = z4;

    for (int k0 = 0; k0 < 768; k0 += 64) {
        __syncthreads();
        #pragma unroll
        for (int it = 0; it < 4; it++) {
            GLL(Asrc + (size_t)(it * 8) * 768 + k0, AsW + it * 512);
            GLL(Bsrc + (size_t)(it * 8) * 768 + k0, BsW + it * 512);
        }
        vmwait0();
        __syncthreads();
        #pragma unroll
        for (int kk = 0; kk < 2; kk++) {
            s16x8 af[4], bf[4];
            #pragma unroll
            for (int i = 0; i < 4; i++) {
                af[i] = *(const s16x8*)&As[(wm * 64 + i * 16 + c15) * 64 + (((kk * 4 + g) ^ cx) * 8)];
                bf[i] = *(const s16x8*)&Bs[(wn * 64 + i * 16 + c15) * 64 + (((kk * 4 + g) ^ cx) * 8)];
            }
            for (int mi = 0; mi < 4; mi++)
                for (int ni = 0; ni < 4; ni++)
                    acc[mi][ni] = __builtin_amdgcn_mfma_f32_16x16x32_bf16(
                        af[mi], bf[ni], acc[mi][ni], 0, 0, 0);
        }
    }

    for (int mi = 0; mi < 4; mi++) {
        int r = m0 + wm * 64 + mi * 16 + g * 4;
        int batch = r >> 11, nbase = r & 2047;
        for (int ni = 0; ni < 4; ni++) {
            int cN = n0 + wn * 64 + ni * 16 + c15;
            int p = cN >> 8, h = (cN >> 6) & 3, d = cN & 63;
            size_t hb = (size_t)((branch * 4 + batch) * 4 + h) * 131072;
            f32x4 v = acc[mi][ni];
            if (p == 2) {
                s16x4 pk;
                for (int rg = 0; rg < 4; rg++) pk[rg] = (short)f2b(v[rg]);
                int pos = nbase & 31;
                int slot = ((pos & 15) >> 2) * 8 + ((pos >> 4) << 2);
                *(s16x4*)(Vt + hb + (size_t)d * 2048 + (nbase & ~31) + slot) = pk;
            } else if (p == 0) {
                for (int rg = 0; rg < 4; rg++)
                    Qo[hb + (size_t)(nbase + rg) * 64 + d] = f2b(v[rg] * QSCALE);
            } else {
                for (int rg = 0; rg < 4; rg++)
                    Ko[hb + (size_t)(nbase + rg) * 64 + d] = f2b(v[rg]);
            }
        }
    }
}

// ---------------- flash attention: gathered q-rows (masked), LDS-staged K/V ----------------
#define ATTN_STEP(KF, VF) do {                                                              \
    _Pragma("unroll")                                                                       \
    for (int s = 0; s < 2; s++) {                                                           \
        f32x4 sa0 = __builtin_amdgcn_mfma_f32_16x16x32_bf16(KF[0][0], qf[s][0], z4, 0, 0, 0); \
        sa0 = __builtin_amdgcn_mfma_f32_16x16x32_bf16(KF[0][1], qf[s][1], sa0, 0, 0, 0);    \
        f32x4 sa1 = __builtin_amdgcn_mfma_f32_16x16x32_bf16(KF[1][0], qf[s][0], z4, 0, 0, 0); \
        sa1 = __builtin_amdgcn_mfma_f32_16x16x32_bf16(KF[1][1], qf[s][1], sa1, 0, 0, 0);    \
        float q0 = fexp2(sa0[0]), q1 = fexp2(sa0[1]);                                       \
        float q2 = fexp2(sa0[2]), q3 = fexp2(sa0[3]);                                       \
        float q4 = fexp2(sa1[0]), q5 = fexp2(sa1[1]);                                       \
        float q6 = fexp2(sa1[2]), q7 = fexp2(sa1[3]);                                       \
        lsp[s] += ((q0 + q1) + (q2 + q3)) + ((q4 + q5) + (q6 + q7));                        \
        u32x4 pw;                                                                           \
        pw[0] = cvtpk(q0, q1); pw[1] = cvtpk(q2, q3);                                       \
        pw[2] = cvtpk(q4, q5); pw[3] = cvtpk(q6, q7);                                       \
        union { u32x4 w; s16x8 h; } pu; pu.w = pw;                                          \
        s16x8 pb = pu.h;                                                                    \
        _Pragma("unroll")                                                                   \
        for (int dt = 0; dt < 4; dt++)                                                      \
            oac[s][dt] = __builtin_amdgcn_mfma_f32_16x16x32_bf16(VF[dt], pb, oac[s][dt], 0, 0, 0); \
    }                                                                                       \
} while (0)

#define STAGE(B, T) do {                                                  \
    const unsigned char* _ks = Ksrc + (size_t)(T) * 8192;                 \
    const unsigned char* _vs = Vsrc + (size_t)(T) * 128;                  \
    unsigned char* _kd = &lds[(B) * 16384 + w * 2048];                    \
    unsigned char* _vd = &lds[(B) * 16384 + 8192 + w * 2048];             \
    GLL(_ks, _kd); GLL(_ks + 1024, _kd + 1024);                           \
    GLL(_vs, _vd); GLL(_vs + 32768, _vd + 1024);                          \
} while (0)

#define TILE_STEP(B) do {                                                               \
    const unsigned char* _KL = &lds[(B) * 16384];                                       \
    const unsigned char* _VL = &lds[(B) * 16384 + 8192];                                \
    s16x8 kf[2][2], vf[4];                                                              \
    _Pragma("unroll")                                                                   \
    for (int t = 0; t < 2; t++)                                                         \
        _Pragma("unroll")                                                               \
        for (int h = 0; h < 2; h++)                                                     \
            kf[t][h] = *(const s16x8*)(_KL + (t * 16 + c) * 128 + (((h * 4 + g) ^ cx) * 16)); \
    _Pragma("unroll")                                                                   \
    for (int dt = 0; dt < 4; dt++)                                                      \
        vf[dt] = *(const s16x8*)(_VL + (dt * 16 + c) * 128 + ((g ^ cx) * 16));          \
    ATTN_STEP(kf, vf);                                                                  \
    _Pragma("unroll")                                                                   \
    for (int t = 0; t < 2; t++)                                                         \
        _Pragma("unroll")                                                               \
        for (int h = 0; h < 2; h++)                                                     \
            kf[t][h] = *(const s16x8*)(_KL + ((t + 2) * 16 + c) * 128 + (((h * 4 + g) ^ cx) * 16)); \
    _Pragma("unroll")                                                                   \
    for (int dt = 0; dt < 4; dt++)                                                      \
        vf[dt] = *(const s16x8*)(_VL + (dt * 16 + c) * 128 + (((4 + g) ^ cx) * 16));    \
    ATTN_STEP(kf, vf);                                                                  \
} while (0)

__global__ __launch_bounds__(256, 4) void attn_kernel(const u16* __restrict__ Qg,
                                                      const u16* __restrict__ Kg,
                                                      const u16* __restrict__ Vg,
                                                      const u16* __restrict__ perm,
                                                      const int* __restrict__ cnt,
                                                      const int* __restrict__ startA,
                                                      u16* __restrict__ Og) {
    __shared__ unsigned char lds[32768];
    const int tid = threadIdx.x;
    const int w = tid >> 6, lane = tid & 63;
    const int b = blockIdx.x;
    const int j = b >> 3;
    const int inst = (b & 7) * 6 + (j % 6);   // XCD-pinned instance
    const int branch = inst >> 4, batch = (inst >> 2) & 3, h = inst & 3;
    const int cb = branch * 4 + batch;
    const int count = min(2048, cnt[cb]);
    const int qbase = (j / 6) * 128;
    if (qbase >= count) return;               // uniform whole-block exit; count >= 1 past here
    const int qt = (j / 6) * 4 + w;           // q-tile of 32 compacted rows
    const int g = lane >> 4, c = lane & 15;
    const int cx = c & 7;
    const u16* ci = perm + batch * 2048 + startA[cb];
    const u16* Qh = Qg + (size_t)inst * 131072;

    const int slot0 = qt * 32 + c, slot1 = slot0 + 16;
    // masked gather: n0/n1 always index REAL Q rows of this instance -> no garbage-magnitude
    // fragments can exist -> Inf/NaN structurally impossible even if metadata is wrong
    const int n0 = ci[slot0 < count ? slot0 : count - 1] & 2047;
    const int n1 = ci[slot1 < count ? slot1 : count - 1] & 2047;

    f32x4 z4 = {0.f, 0.f, 0.f, 0.f};
    s16x8 qf[2][2];
    #pragma unroll
    for (int kk = 0; kk < 2; kk++) {
        qf[0][kk] = *(const s16x8*)(Qh + (size_t)n0 * 64 + kk * 32 + g * 8);
        qf[1][kk] = *(const s16x8*)(Qh + (size_t)n1 * 64 + kk * 32 + g * 8);
    }

    f32x4 oac[2][4];
    #pragma unroll
    for (int s = 0; s < 2; s++)
        #pragma unroll
        for (int dt = 0; dt < 4; dt++) oac[s][dt] = z4;
    float lsp[2] = {0.f, 0.f};

    const int swz = (((lane & 7) ^ ((lane >> 3) & 7)) << 4);
    const unsigned char* Ksrc = (const unsigned char*)(Kg + (size_t)inst * 131072)
                                + w * 2048 + ((lane >> 3) << 7) + swz;
    const unsigned char* Vsrc = (const unsigned char*)(Vg + (size_t)inst * 131072)
                                + (size_t)w * 65536 + ((lane >> 3) << 12) + swz;

    STAGE(0, 0);
    vmwait0();
    __syncthreads();
    for (int t2 = 0; t2 < 32; t2++) {
        int cur = t2 & 1;
        if (t2 + 1 < 32) STAGE(cur ^ 1, t2 + 1);
        TILE_STEP(cur);
        vmwait0();
        __syncthreads();
    }

    // write ALL 128 slots of this block (slots >= count hold duplicated real rows):
    // Ob is fully initialized over every row proj will stage
    #pragma unroll
    for (int s = 0; s < 2; s++) {
        float ls = lsp[s];
        ls += __shfl_xor(ls, 16);
        ls += __shfl_xor(ls, 32);
        float inv = 1.0f / ls;
        int slot = qt * 32 + s * 16 + c;
        u16* dst = Og + ((size_t)cb * 2048 + slot) * 256 + h * 64;
        #pragma unroll
        for (int dt = 0; dt < 4; dt++) {
            s16x4 ob;
            for (int rg = 0; rg < 4; rg++) ob[rg] = (short)f2b(oac[s][dt][rg] * inv);
            *(s16x4*)(dst + dt * 16 + g * 4) = ob;
        }
    }
}

// ---------------- proj GEMM: contiguous compacted rows (R9-style staging), masked scatter ----------------
__global__ __launch_bounds__(256) void proj_gemm_kernel(const u16* __restrict__ Oall,
                                                        const u16* __restrict__ Wpt_all,
                                                        const u16* __restrict__ perm,
                                                        const int* __restrict__ cnt,
                                                        const int* __restrict__ startA,
                                                        const float* __restrict__ bp1,
                                                        const float* __restrict__ bp2,
                                                        const float* __restrict__ bp3,
                                                        float* __restrict__ out) {
    __shared__ u16 As[128 * 64];
    __shared__ u16 Bs[128 * 64];
    const int tid = threadIdx.x;
    const int lane = tid & 63, w = tid >> 6, wm = w >> 1, wn = w & 1;
    const int g = lane >> 4, c15 = lane & 15;
    const int cx = c15 & 7;
    const int branch = blockIdx.z;
    const int m0 = blockIdx.y * 128, n0 = blockIdx.x * 128;
    const int batch = m0 >> 11;
    const int cb = branch * 4 + batch;
    const int count = min(2048, cnt[cb]);
    const int pbase = m0 & 2047;
    if (pbase >= count) return;               // same condition as attn's exit -> staged rows all written
    const u16* A = Oall + (size_t)branch * 8192 * 256;
    const u16* Bt = Wpt_all + (size_t)branch * 196608;
    const float* bp = (branch == 0) ? bp1 : ((branch == 1) ? bp2 : bp3);

    const int l8 = lane >> 3;
    const int ch = (lane & 7) ^ l8;
    const u16* Asrc = A + (size_t)(m0 + w * 32 + l8) * 256 + ch * 8;
    const u16* Bsrc = Bt + (size_t)(n0 + w * 32 + l8) * 256 + ch * 8;
    u16* AsW = As + w * 2048;
    u16* BsW = Bs + w * 2048;

    f32x4 z4 = {0.f, 0.f, 0.f, 0.f};
    f32x4 acc[4][4];
    for (int mi = 0; mi < 4; mi++)
        for (int ni = 0; ni < 4; ni++) acc[mi][ni] = z4;

    for (int k0 = 0; k0 < 256; k0 += 64) {
        __syncthreads();
        #pragma unroll
        for (int it = 0; it < 4; it++) {
            GLL(Asrc + (size_t)(it * 8) * 256 + k0, AsW + it * 512);
            GLL(Bsrc + (size_t)(it * 8) * 256 + k0, BsW + it * 512);
        }
        vmwait0();
        __syncthreads();
        #pragma unroll
        for (int kk = 0; kk < 2; kk++) {
            s16x8 af[4], bf[4];
            #pragma unroll
            for (int i = 0; i < 4; i++) {
                af[i] = *(const s16x8*)&As[(wm * 64 + i * 16 + c15) * 64 + (((kk * 4 + g) ^ cx) * 8)];
                bf[i] = *(const s16x8*)&Bs[(wn * 64 + i * 16 + c15) * 64 + (((kk * 4 + g) ^ cx) * 8)];
            }
            for (int mi = 0; mi < 4; mi++)
                for (int ni = 0; ni < 4; ni++)
                    acc[mi][ni] = __builtin_amdgcn_mfma_f32_16x16x32_bf16(
                        af[mi], bf[ni], acc[mi][ni], 0, 0, 0);
        }
    }

    const u16* ci = perm + batch * 2048 + startA[cb];
    for (int mi = 0; mi < 4; mi++) {
        int r = pbase + wm * 64 + mi * 16 + g * 4;
        for (int ni = 0; ni < 4; ni++) {
            int cN = n0 + wn * 64 + ni * 16 + c15;
            float bj = bp[cN];
            f32x4 v = acc[mi][ni];
            for (int rg = 0; rg < 4; rg++) {
                int slot = r + rg;
                if (slot < count) {
                    int t = batch * 2048 + (ci[slot] & 2047);
                    float wv = v[rg] + bj;
                    out[(size_t)t * 768 + cN] = wv;                 // xo
                    out[6291456u + (size_t)t * 768 + cN] = wv;      // xd
                }
            }
        }
    }
}

extern "C" void kernel_launch(void* const* d_in, const int* in_sizes, int n_in,
                              void* d_out, int out_size, void* d_ws, size_t ws_size,
                              hipStream_t stream) {
    const float* x   = (const float*)d_in[0];
    const float* Wq1 = (const float*)d_in[1];
    const float* Wq2 = (const float*)d_in[2];
    const float* Wq3 = (const float*)d_in[3];
    const float* Wp1 = (const float*)d_in[4];
    const float* bp1 = (const float*)d_in[5];
    const float* Wp2 = (const float*)d_in[6];
    const float* bp2 = (const float*)d_in[7];
    const float* Wp3 = (const float*)d_in[8];
    const float* bp3 = (const float*)d_in[9];
    const float* Wg  = (const float*)d_in[10];
    float* out = (float*)d_out;

    char* ws = (char*)d_ws;
    u16* xb    = (u16*)(ws + 0);          // 12582912 B
    u16* wqt   = (u16*)(ws + 12582912);   // 3538944 B
    u16* wpt   = (u16*)(ws + 16121856);   // 1179648 B
    u16* Qb    = (u16*)(ws + 17301504);   // 12582912 B (48 x [2048][64], pre-scaled)
    u16* Kb    = (u16*)(ws + 29884416);   // 12582912 B
    u16* Vtb   = (u16*)(ws + 42467328);   // 12582912 B (48 x [64][2048], slot-remapped)
    u16* Ob    = (u16*)(ws + 55050240);   // 12582912 B (12 x [2048][256], compacted rows)
    // packed inside the R2-R9-proven [67633152, 67665920) region:
    u16* perm  = (u16*)(ws + 67633152);   // 16384 B (4 x 2048 u16)
    int* cnt   = (int*)(ws + 67649536);   // 48 B
    int* start = (int*)(ws + 67649600);   // 48 B
    u8*  kArr  = (u8*) (ws + 67649664);   // 8192 B  -> end 67657856 < 67665920

    castgate_kernel<<<2048, 256, 0, stream>>>(x, Wg, xb, kArr, out);
    compact_kernel<<<4, 64, 0, stream>>>(kArr, perm, cnt, start);
    wcast_all_kernel<<<dim3(576, 6), 256, 0, stream>>>(Wq1, Wq2, Wq3, Wp1, Wp2, Wp3, wqt, wpt);
    qkv_gemm_kernel<<<dim3(6, 64, 3), 256, 0, stream>>>(xb, wqt, Qb, Kb, Vtb);
    attn_kernel<<<768, 256, 0, stream>>>(Qb, Kb, Vtb, perm, cnt, start, Ob);
    proj_gemm_kernel<<<dim3(6, 64, 3), 256, 0, stream>>>(Ob, wpt, perm, cnt, start, bp1, bp2, bp3, out);
}

// Round 13
// 135.247 us; speedup vs baseline: 2.8877x; 1.0481x over previous
//
#include <hip/hip_runtime.h>

typedef short s16x4 __attribute__((ext_vector_type(4)));
typedef short s16x8 __attribute__((ext_vector_type(8)));
typedef float f32x4 __attribute__((ext_vector_type(4)));
typedef unsigned u32x4 __attribute__((ext_vector_type(4)));
typedef unsigned short u16;
typedef unsigned char u8;

__device__ __forceinline__ u16 f2b(float f) {
    union { float f; unsigned u; } v; v.f = f;
    unsigned r = v.u + 0x7FFFu + ((v.u >> 16) & 1u);
    return (u16)(r >> 16);
}

__device__ __forceinline__ float fexp2(float x) {
    float r; asm("v_exp_f32 %0, %1" : "=v"(r) : "v"(x)); return r;
}

__device__ __forceinline__ unsigned cvtpk(float lo, float hi) {
    unsigned r; asm("v_cvt_pk_bf16_f32 %0, %1, %2" : "=v"(r) : "v"(lo), "v"(hi)); return r;
}

__device__ __forceinline__ void GLL(const void* g, void* l) {
    __builtin_amdgcn_global_load_lds(
        (const __attribute__((address_space(1))) unsigned int*)g,
        (__attribute__((address_space(3))) unsigned int*)l, 16, 0, 0);
}

// explicit DMA drain before barriers that publish staged LDS (R6/R7 race evidence)
__device__ __forceinline__ void vmwait0() {
    asm volatile("s_waitcnt vmcnt(0)" ::: "memory");
    __builtin_amdgcn_sched_barrier(0);
}

// Q pre-scale: hd^-0.5 * log2(e) so attention uses v_exp_f32 (2^x) directly
#define QSCALE 0.1803368801111244f

// ---------------- fused prolog: castgate (blocks 0..2047) + wcast (blocks 2048..4351) ----------------
__global__ __launch_bounds__(256) void prolog_kernel(const float* __restrict__ x,
                                                     const float* __restrict__ Wg,
                                                     u16* __restrict__ xb,
                                                     u8* __restrict__ kArr,
                                                     float* __restrict__ out,
                                                     const float* __restrict__ W0,
                                                     const float* __restrict__ W1,
                                                     const float* __restrict__ W2,
                                                     const float* __restrict__ W3,
                                                     const float* __restrict__ W4,
                                                     const float* __restrict__ W5,
                                                     u16* __restrict__ wqt,
                                                     u16* __restrict__ wpt) {
    __shared__ u16 tile[32][34];
    if (blockIdx.x < 2048) {
        // ---- castgate: cast x->bf16 + gate argmax ----
        int t = blockIdx.x * 4 + (threadIdx.x >> 6);
        int lane = threadIdx.x & 63;
        const float* xr = x + (size_t)t * 768;
        u16* xw = xb + (size_t)t * 768;
        float z0 = 0.f, z1 = 0.f, z2 = 0.f;
        #pragma unroll
        for (int s = 0; s < 3; s++) {
            int base = s * 256 + lane * 4;
            f32x4 v = *(const f32x4*)(xr + base);
            s16x4 o;
            #pragma unroll
            for (int j = 0; j < 4; j++) {
                o[j] = (short)f2b(v[j]);
                z0 = fmaf(v[j], Wg[(base + j) * 3 + 0], z0);
                z1 = fmaf(v[j], Wg[(base + j) * 3 + 1], z1);
                z2 = fmaf(v[j], Wg[(base + j) * 3 + 2], z2);
            }
            *(s16x4*)(xw + base) = o;
        }
        for (int o = 32; o; o >>= 1) {
            z0 += __shfl_xor(z0, o);
            z1 += __shfl_xor(z1, o);
            z2 += __shfl_xor(z2, o);
        }
        if (lane == 0) {
            int k = 0; float b = z0;
            if (z1 > b) { b = z1; k = 1; }
            if (z2 > b) { b = z2; k = 2; }
            out[12582912 + t] = (float)k;   // idx output
            kArr[t] = (u8)k;
        }
    } else {
        // ---- wcast: transpose + cast weights, LDS 32x32 tiles ----
        int wb = blockIdx.x - 2048;          // 0..2303
        int y, bt;
        if (wb < 1728) { y = wb / 576; bt = wb % 576; }
        else           { int w2 = wb - 1728; y = 3 + w2 / 192; bt = w2 % 192; }
        const float* W; u16* dst; int K;
        if (y < 3) { W = (y == 0) ? W0 : (y == 1) ? W1 : W2; dst = wqt + y * 589824; K = 768; }
        else       { W = (y == 3) ? W3 : (y == 4) ? W4 : W5; dst = wpt + (y - 3) * 196608; K = 256; }
        int ktiles = K >> 5;
        int kt = bt % ktiles, nt = bt / ktiles;
        int tx = threadIdx.x & 31, ty = threadIdx.x >> 5;
        #pragma unroll
        for (int i = 0; i < 4; i++) {
            int k = kt * 32 + ty + i * 8;
            tile[ty + i * 8][tx] = f2b(W[(size_t)k * 768 + nt * 32 + tx]);
        }
        __syncthreads();
        #pragma unroll
        for (int i = 0; i < 4; i++) {
            int n = nt * 32 + ty + i * 8;
            dst[(size_t)n * K + kt * 32 + tx] = tile[tx][ty + i * 8];
        }
    }
}

// ---------------- deterministic ballot compaction: per-batch permutation ----------------
__global__ __launch_bounds__(64) void compact_kernel(const u8* __restrict__ kArr,
                                                     u16* __restrict__ perm,
                                                     int* __restrict__ cnt,
                                                     int* __restrict__ startA) {
    int batch = blockIdx.x;
    int lane = threadIdx.x;
    const u8* ka = kArr + batch * 2048;
    u16* pm = perm + batch * 2048;
    int off = 0;
    for (int br = 0; br < 3; br++) {
        int c = 0;
        for (int b0 = 0; b0 < 2048; b0 += 64) {
            bool p = (ka[b0 + lane] == (u8)br);
            unsigned long long m = __ballot(p);
            int rank = __popcll(m & ((1ull << lane) - 1ull));
            if (p) pm[off + c + rank] = (u16)(b0 + lane);
            c += __popcll(m);
        }
        if (lane == 0) { cnt[br * 4 + batch] = c; startA[br * 4 + batch] = off; }
        off += c;
    }
}

// ---------------- QKV GEMM: GLL-staged, XCD-pinned m-panels ----------------
// b -> xcd=b&7; all 18 (n,branch) blocks of one m-panel land on one XCD:
// per-XCD L2 working set = 8 A-panels (1.6MB transient) + all B (3.5MB) < 4MB.
__global__ __launch_bounds__(256) void qkv_gemm_kernel(const u16* __restrict__ A,
                                                       const u16* __restrict__ Bt_all,
                                                       u16* __restrict__ Qo,
                                                       u16* __restrict__ Ko,
                                                       u16* __restrict__ Vt) {
    __shared__ u16 As[128 * 64];
    __shared__ u16 Bs[128 * 64];
    const int tid = threadIdx.x;
    const int lane = tid & 63, w = tid >> 6, wm = w >> 1, wn = w & 1;
    const int g = lane >> 4, c15 = lane & 15;
    const int cx = c15 & 7;
    const int b = blockIdx.x;
    const int j = b >> 3;
    const int v = j % 18;
    const int branch = v / 6;
    const int m0 = ((b & 7) * 8 + j / 18) * 128;
    const int n0 = (v % 6) * 128;
    const u16* Bt = Bt_all + (size_t)branch * 589824;

    const int l8 = lane >> 3;
    const int ch = (lane & 7) ^ l8;      // swizzled source chunk: LDS[row][j] = G[row][j^(row&7)]
    const u16* Asrc = A + (size_t)(m0 + w * 32 + l8) * 768 + ch * 8;
    const u16* Bsrc = Bt + (size_t)(n0 + w * 32 + l8) * 768 + ch * 8;
    u16* AsW = As + w * 2048;
    u16* BsW = Bs + w * 2048;

    f32x4 z4 = {0.f, 0.f, 0.f, 0.f};
    f32x4 acc[4][4];
    for (int mi = 0; mi < 4; mi++)
        for (int ni = 0; ni < 4; ni++) acc[mi][ni] = z4;

    for (int k0 = 0; k0 < 768; k0 += 64) {
        __syncthreads();
        #pragma unroll
        for (int it = 0; it < 4; it++) {
            GLL(Asrc + (size_t)(it * 8) * 768 + k0, AsW + it * 512);
            GLL(Bsrc + (size_t)(it * 8) * 768 + k0, BsW + it * 512);
        }
        vmwait0();
        __syncthreads();
        #pragma unroll
        for (int kk = 0; kk < 2; kk++) {
            s16x8 af[4], bf[4];
            #pragma unroll
            for (int i = 0; i < 4; i++) {
                af[i] = *(const s16x8*)&As[(wm * 64 + i * 16 + c15) * 64 + (((kk * 4 + g) ^ cx) * 8)];
                bf[i] = *(const s16x8*)&Bs[(wn * 64 + i * 16 + c15) * 64 + (((kk * 4 + g) ^ cx) * 8)];
            }
            for (int mi = 0; mi < 4; mi++)
                for (int ni = 0; ni < 4; ni++)
                    acc[mi][ni] = __builtin_amdgcn_mfma_f32_16x16x32_bf16(
                        af[mi], bf[ni], acc[mi][ni], 0, 0, 0);
        }
    }

    for (int mi = 0; mi < 4; mi++) {
        int r = m0 + wm * 64 + mi * 16 + g * 4;
        int batch = r >> 11, nbase = r & 2047;
        for (int ni = 0; ni < 4; ni++) {
            int cN = n0 + wn * 64 + ni * 16 + c15;
            int p = cN >> 8, h = (cN >> 6) & 3, d = cN & 63;
            size_t hb = (size_t)((branch * 4 + batch) * 4 + h) * 131072;
            f32x4 vv = acc[mi][ni];
            if (p == 2) {
                s16x4 pk;
                for (int rg = 0; rg < 4; rg++) pk[rg] = (short)f2b(vv[rg]);
                int pos = nbase & 31;
                int slot = ((pos & 15) >> 2) * 8 + ((pos >> 4) << 2);
                *(s16x4*)(Vt + hb + (size_t)d * 2048 + (nbase & ~31) + slot) = pk;
            } else if (p == 0) {
                for (int rg = 0; rg < 4; rg++)
                    Qo[hb + (size_t)(nbase + rg) * 64 + d] = f2b(vv[rg] * QSCALE);
            } else {
                for (int rg = 0; rg < 4; rg++)
                    Ko[hb + (size_t)(nbase + rg) * 64 + d] = f2b(vv[rg]);
            }
        }
    }
}

// ---------------- flash attention: gathered q-rows (masked), LDS-staged K/V ----------------
#define ATTN_STEP(KF, VF) do {                                                              \
    _Pragma("unroll")                                                                       \
    for (int s = 0; s < 2; s++) {                                                           \
        f32x4 sa0 = __builtin_amdgcn_mfma_f32_16x16x32_bf16(KF[0][0], qf[s][0], z4, 0, 0, 0); \
        sa0 = __builtin_amdgcn_mfma_f32_16x16x32_bf16(KF[0][1], qf[s][1], sa0, 0, 0, 0);    \
        f32x4 sa1 = __builtin_amdgcn_mfma_f32_16x16x32_bf16(KF[1][0], qf[s][0], z4, 0, 0, 0); \
        sa1 = __builtin_amdgcn_mfma_f32_16x16x32_bf16(KF[1][1], qf[s][1], sa1, 0, 0, 0);    \
        float q0 = fexp2(sa0[0]), q1 = fexp2(sa0[1]);                                       \
        float q2 = fexp2(sa0[2]), q3 = fexp2(sa0[3]);                                       \
        float q4 = fexp2(sa1[0]), q5 = fexp2(sa1[1]);                                       \
        float q6 = fexp2(sa1[2]), q7 = fexp2(sa1[3]);                                       \
        lsp[s] += ((q0 + q1) + (q2 + q3)) + ((q4 + q5) + (q6 + q7));                        \
        u32x4 pw;                                                                           \
        pw[0] = cvtpk(q0, q1); pw[1] = cvtpk(q2, q3);                                       \
        pw[2] = cvtpk(q4, q5); pw[3] = cvtpk(q6, q7);                                       \
        union { u32x4 w; s16x8 h; } pu; pu.w = pw;                                          \
        s16x8 pb = pu.h;                                                                    \
        _Pragma("unroll")                                                                   \
        for (int dt = 0; dt < 4; dt++)                                                      \
            oac[s][dt] = __builtin_amdgcn_mfma_f32_16x16x32_bf16(VF[dt], pb, oac[s][dt], 0, 0, 0); \
    }                                                                                       \
} while (0)

#define STAGE(B, T) do {                                                  \
    const unsigned char* _ks = Ksrc + (size_t)(T) * 8192;                 \
    const unsigned char* _vs = Vsrc + (size_t)(T) * 128;                  \
    unsigned char* _kd = &lds[(B) * 16384 + w * 2048];                    \
    unsigned char* _vd = &lds[(B) * 16384 + 8192 + w * 2048];             \
    GLL(_ks, _kd); GLL(_ks + 1024, _kd + 1024);                           \
    GLL(_vs, _vd); GLL(_vs + 32768, _vd + 1024);                          \
} while (0)

#define TILE_STEP(B) do {                                                               \
    const unsigned char* _KL = &lds[(B) * 16384];                                       \
    const unsigned char* _VL = &lds[(B) * 16384 + 8192];                                \
    s16x8 kf[2][2], vf[4];                                                              \
    _Pragma("unroll")                                                                   \
    for (int t = 0; t < 2; t++)                                                         \
        _Pragma("unroll")                                                               \
        for (int h = 0; h < 2; h++)                                                     \
            kf[t][h] = *(const s16x8*)(_KL + (t * 16 + c) * 128 + (((h * 4 + g) ^ cx) * 16)); \
    _Pragma("unroll")                                                                   \
    for (int dt = 0; dt < 4; dt++)                                                      \
        vf[dt] = *(const s16x8*)(_VL + (dt * 16 + c) * 128 + ((g ^ cx) * 16));          \
    ATTN_STEP(kf, vf);                                                                  \
    _Pragma("unroll")                                                                   \
    for (int t = 0; t < 2; t++)                                                         \
        _Pragma("unroll")                                                               \
        for (int h = 0; h < 2; h++)                                                     \
            kf[t][h] = *(const s16x8*)(_KL + ((t + 2) * 16 + c) * 128 + (((h * 4 + g) ^ cx) * 16)); \
    _Pragma("unroll")                                                                   \
    for (int dt = 0; dt < 4; dt++)                                                      \
        vf[dt] = *(const s16x8*)(_VL + (dt * 16 + c) * 128 + (((4 + g) ^ cx) * 16));    \
    ATTN_STEP(kf, vf);                                                                  \
} while (0)

__global__ __launch_bounds__(256, 4) void attn_kernel(const u16* __restrict__ Qg,
                                                      const u16* __restrict__ Kg,
                                                      const u16* __restrict__ Vg,
                                                      const u16* __restrict__ perm,
                                                      const int* __restrict__ cnt,
                                                      const int* __restrict__ startA,
                                                      u16* __restrict__ Og) {
    __shared__ unsigned char lds[32768];
    const int tid = threadIdx.x;
    const int w = tid >> 6, lane = tid & 63;
    const int b = blockIdx.x;
    const int j = b >> 3;
    const int inst = (b & 7) * 6 + (j % 6);   // XCD-pinned instance
    const int branch = inst >> 4, batch = (inst >> 2) & 3, h = inst & 3;
    const int cb = branch * 4 + batch;
    const int count = min(2048, cnt[cb]);
    const int qbase = (j / 6) * 128;
    if (qbase >= count) return;               // uniform whole-block exit; count >= 1 past here
    const int qt = (j / 6) * 4 + w;           // q-tile of 32 compacted rows
    const int g = lane >> 4, c = lane & 15;
    const int cx = c & 7;
    const u16* ci = perm + batch * 2048 + startA[cb];
    const u16* Qh = Qg + (size_t)inst * 131072;

    const int slot0 = qt * 32 + c, slot1 = slot0 + 16;
    const int n0 = ci[slot0 < count ? slot0 : count - 1] & 2047;
    const int n1 = ci[slot1 < count ? slot1 : count - 1] & 2047;

    f32x4 z4 = {0.f, 0.f, 0.f, 0.f};
    s16x8 qf[2][2];
    #pragma unroll
    for (int kk = 0; kk < 2; kk++) {
        qf[0][kk] = *(const s16x8*)(Qh + (size_t)n0 * 64 + kk * 32 + g * 8);
        qf[1][kk] = *(const s16x8*)(Qh + (size_t)n1 * 64 + kk * 32 + g * 8);
    }

    f32x4 oac[2][4];
    #pragma unroll
    for (int s = 0; s < 2; s++)
        #pragma unroll
        for (int dt = 0; dt < 4; dt++) oac[s][dt] = z4;
    float lsp[2] = {0.f, 0.f};

    const int swz = (((lane & 7) ^ ((lane >> 3) & 7)) << 4);
    const unsigned char* Ksrc = (const unsigned char*)(Kg + (size_t)inst * 131072)
                                + w * 2048 + ((lane >> 3) << 7) + swz;
    const unsigned char* Vsrc = (const unsigned char*)(Vg + (size_t)inst * 131072)
                                + (size_t)w * 65536 + ((lane >> 3) << 12) + swz;

    STAGE(0, 0);
    vmwait0();
    __syncthreads();
    for (int t2 = 0; t2 < 32; t2++) {
        int cur = t2 & 1;
        if (t2 + 1 < 32) STAGE(cur ^ 1, t2 + 1);
        TILE_STEP(cur);
        vmwait0();
        __syncthreads();
    }

    // write ALL 128 slots of this block (slots >= count hold duplicated real rows)
    #pragma unroll
    for (int s = 0; s < 2; s++) {
        float ls = lsp[s];
        ls += __shfl_xor(ls, 16);
        ls += __shfl_xor(ls, 32);
        float inv = 1.0f / ls;
        int slot = qt * 32 + s * 16 + c;
        u16* dst = Og + ((size_t)cb * 2048 + slot) * 256 + h * 64;
        #pragma unroll
        for (int dt = 0; dt < 4; dt++) {
            s16x4 ob;
            for (int rg = 0; rg < 4; rg++) ob[rg] = (short)f2b(oac[s][dt][rg] * inv);
            *(s16x4*)(dst + dt * 16 + g * 4) = ob;
        }
    }
}

// ---------------- proj GEMM: contiguous compacted rows, masked scatter ----------------
__global__ __launch_bounds__(256) void proj_gemm_kernel(const u16* __restrict__ Oall,
                                                        const u16* __restrict__ Wpt_all,
                                                        const u16* __restrict__ perm,
                                                        const int* __restrict__ cnt,
                                                        const int* __restrict__ startA,
                                                        const float* __restrict__ bp1,
                                                        const float* __restrict__ bp2,
                                                        const float* __restrict__ bp3,
                                                        float* __restrict__ out) {
    __shared__ u16 As[128 * 64];
    __shared__ u16 Bs[128 * 64];
    const int tid = threadIdx.x;
    const int lane = tid & 63, w = tid >> 6, wm = w >> 1, wn = w & 1;
    const int g = lane >> 4, c15 = lane & 15;
    const int cx = c15 & 7;
    const int branch = blockIdx.z;
    const int m0 = blockIdx.y * 128, n0 = blockIdx.x * 128;
    const int batch = m0 >> 11;
    const int cb = branch * 4 + batch;
    const int count = min(2048, cnt[cb]);
    const int pbase = m0 & 2047;
    if (pbase >= count) return;
    const u16* A = Oall + (size_t)branch * 8192 * 256;
    const u16* Bt = Wpt_all + (size_t)branch * 196608;
    const float* bp = (branch == 0) ? bp1 : ((branch == 1) ? bp2 : bp3);

    const int l8 = lane >> 3;
    const int ch = (lane & 7) ^ l8;
    const u16* Asrc = A + (size_t)(m0 + w * 32 + l8) * 256 + ch * 8;
    const u16* Bsrc = Bt + (size_t)(n0 + w * 32 + l8) * 256 + ch * 8;
    u16* AsW = As + w * 2048;
    u16* BsW = Bs + w * 2048;

    f32x4 z4 = {0.f, 0.f, 0.f, 0.f};
    f32x4 acc[4][4];
    for (int mi = 0; mi < 4; mi++)
        for (int ni = 0; ni < 4; ni++) acc[mi][ni] = z4;

    for (int k0 = 0; k0 < 256; k0 += 64) {
        __syncthreads();
        #pragma unroll
        for (int it = 0; it < 4; it++) {
            GLL(Asrc + (size_t)(it * 8) * 256 + k0, AsW + it * 512);
            GLL(Bsrc + (size_t)(it * 8) * 256 + k0, BsW + it * 512);
        }
        vmwait0();
        __syncthreads();
        #pragma unroll
        for (int kk = 0; kk < 2; kk++) {
            s16x8 af[4], bf[4];
            #pragma unroll
            for (int i = 0; i < 4; i++) {
                af[i] = *(const s16x8*)&As[(wm * 64 + i * 16 + c15) * 64 + (((kk * 4 + g) ^ cx) * 8)];
                bf[i] = *(const s16x8*)&Bs[(wn * 64 + i * 16 + c15) * 64 + (((kk * 4 + g) ^ cx) * 8)];
            }
            for (int mi = 0; mi < 4; mi++)
                for (int ni = 0; ni < 4; ni++)
                    acc[mi][ni] = __builtin_amdgcn_mfma_f32_16x16x32_bf16(
                        af[mi], bf[ni], acc[mi][ni], 0, 0, 0);
        }
    }

    const u16* ci = perm + batch * 2048 + startA[cb];
    for (int mi = 0; mi < 4; mi++) {
        int r = pbase + wm * 64 + mi * 16 + g * 4;
        for (int ni = 0; ni < 4; ni++) {
            int cN = n0 + wn * 64 + ni * 16 + c15;
            float bj = bp[cN];
            f32x4 v = acc[mi][ni];
            for (int rg = 0; rg < 4; rg++) {
                int slot = r + rg;
                if (slot < count) {
                    int t = batch * 2048 + (ci[slot] & 2047);
                    float wv = v[rg] + bj;
                    out[(size_t)t * 768 + cN] = wv;                 // xo
                    out[6291456u + (size_t)t * 768 + cN] = wv;      // xd
                }
            }
        }
    }
}

extern "C" void kernel_launch(void* const* d_in, const int* in_sizes, int n_in,
                              void* d_out, int out_size, void* d_ws, size_t ws_size,
                              hipStream_t stream) {
    const float* x   = (const float*)d_in[0];
    const float* Wq1 = (const float*)d_in[1];
    const float* Wq2 = (const float*)d_in[2];
    const float* Wq3 = (const float*)d_in[3];
    const float* Wp1 = (const float*)d_in[4];
    const float* bp1 = (const float*)d_in[5];
    const float* Wp2 = (const float*)d_in[6];
    const float* bp2 = (const float*)d_in[7];
    const float* Wp3 = (const float*)d_in[8];
    const float* bp3 = (const float*)d_in[9];
    const float* Wg  = (const float*)d_in[10];
    float* out = (float*)d_out;

    char* ws = (char*)d_ws;
    u16* xb    = (u16*)(ws + 0);          // 12582912 B
    u16* wqt   = (u16*)(ws + 12582912);   // 3538944 B
    u16* wpt   = (u16*)(ws + 16121856);   // 1179648 B
    u16* Qb    = (u16*)(ws + 17301504);   // 12582912 B (48 x [2048][64], pre-scaled)
    u16* Kb    = (u16*)(ws + 29884416);   // 12582912 B
    u16* Vtb   = (u16*)(ws + 42467328);   // 12582912 B (48 x [64][2048], slot-remapped)
    u16* Ob    = (u16*)(ws + 55050240);   // 12582912 B (12 x [2048][256], compacted rows)
    u16* perm  = (u16*)(ws + 67633152);   // 16384 B (4 x 2048 u16)
    int* cnt   = (int*)(ws + 67649536);   // 48 B
    int* start = (int*)(ws + 67649600);   // 48 B
    u8*  kArr  = (u8*) (ws + 67649664);   // 8192 B  -> end 67657856

    prolog_kernel<<<4352, 256, 0, stream>>>(x, Wg, xb, kArr, out,
                                            Wq1, Wq2, Wq3, Wp1, Wp2, Wp3, wqt, wpt);
    compact_kernel<<<4, 64, 0, stream>>>(kArr, perm, cnt, start);
    qkv_gemm_kernel<<<1152, 256, 0, stream>>>(xb, wqt, Qb, Kb, Vtb);
    attn_kernel<<<768, 256, 0, stream>>>(Qb, Kb, Vtb, perm, cnt, start, Ob);
    proj_gemm_kernel<<<dim3(6, 64, 3), 256, 0, stream>>>(Ob, wpt, perm, cnt, start, bp1, bp2, bp3, out);
}